// Round 1
// baseline (4329.624 us; speedup 1.0000x reference)
//
#include <hip/hip_runtime.h>
#include <hip/hip_bf16.h>
#include <cmath>

// Problem constants
#define BB 64
#define NN 512
#define NBS 8
#define EE 2048
#define HH 128
#define LL 3
#define KK 4
#define AF 82
#define BF 6
#define SLAB 4194304   // B*N*H floats

__device__ __forceinline__ float gelu1(float x){ return 0.5f*x*(1.f+erff(x*0.7071067811865475f)); }
__device__ __forceinline__ float sig1(float x){ return 1.f/(1.f+expf(-x)); }

#define FMA4(acc, a, w) { (acc).x += (a)*(w).x; (acc).y += (a)*(w).y; (acc).z += (a)*(w).z; (acc).w += (a)*(w).w; }

// ---------------------------------------------------------------------------
// Generic tiled fp32 GEMM: C[M,128] = epilogue(A[M,K] @ W[K,128] + bias)
// AMODE: 0 contiguous A; 1 atom-table gather * vmask; 2 concat(A,A2) K=256;
//        3 u1 gather concat(vf[g1], e_init[g2]) K=134
// EMODE: 0 bias; 1 gelu (+ optional dual store C2); 2 tanh;
//        3 theta-blend: p0*(acc+b) + p1*extraM;
//        4 z-gate: z=sig(acc+b+extraB[b]); C=(1-z)*extraM + z*extraB2[b]
//        5 gelu * nbs_mask, segment-sum over 8 rows -> C[M/8,128]
// gridDim.z: weight/bias/C offset per z (for per-head batches)
// ---------------------------------------------------------------------------
template<int AMODE, int EMODE>
__global__ __launch_bounds__(256) void gemm_kernel(
    const float* __restrict__ A, const float* __restrict__ A2,
    const float* __restrict__ W, const float* __restrict__ bias,
    float* __restrict__ C, float* __restrict__ C2,
    int M, int K,
    const int* __restrict__ g1, const int* __restrict__ g2,
    const float* __restrict__ vmask, const float* __restrict__ nbm,
    const float* __restrict__ extraM, const float* __restrict__ extraB,
    const float* __restrict__ extraB2,
    float p0, float p1, int rowsPerB, unsigned long long zCs)
{
    __shared__ __align__(16) float As[32*68];    // transposed: As[k][row], LD=68
    __shared__ __align__(16) float Ws[32*132];   // Ws[k][col], LD=132
    const int t  = threadIdx.x;
    const int m0 = blockIdx.x * 64;
    const int z  = blockIdx.z;
    W    += (size_t)z * K * 128;
    bias += (size_t)z * 128;
    C    += (size_t)z * zCs;

    const int rg = t >> 5;      // 0..7 -> rows rg*8..rg*8+7
    const int cg = t & 31;      // cols cg*4..cg*4+3
    float4 c[8];
    #pragma unroll
    for (int r = 0; r < 8; ++r) c[r] = make_float4(0.f,0.f,0.f,0.f);

    const int nk = (K + 31) >> 5;
    for (int kc = 0; kc < nk; ++kc) {
        const int k0 = kc * 32;
        // stage W chunk [32][128]
        #pragma unroll
        for (int it = 0; it < 16; ++it) {
            int id = it*256 + t; int kk = id >> 7; int col = id & 127; int kg = k0 + kk;
            Ws[kk*132 + col] = (kg < K) ? W[(size_t)kg*128 + col] : 0.f;
        }
        // stage A chunk transposed [32][64]
        #pragma unroll
        for (int it = 0; it < 8; ++it) {
            int id = it*256 + t; int kl = id & 31; int row = id >> 5; int kg = k0 + kl;
            float v = 0.f;
            if (AMODE == 0) {
                if (kg < K) v = A[(size_t)(m0+row)*K + kg];
            } else if (AMODE == 1) {
                if (kg < K) { int a = g1[m0+row]; v = A[(size_t)a*K + kg] * vmask[m0+row]; }
            } else if (AMODE == 2) {
                if (kg < 128) v = A[(size_t)(m0+row)*128 + kg];
                else if (kg < K) v = A2[(size_t)(m0+row)*128 + (kg-128)];
            } else { // 3: u1 gather
                if (kg < 128) v = A[(size_t)g1[m0+row]*128 + kg];
                else if (kg < K) v = A2[(size_t)g2[m0+row]*6 + (kg-128)];
            }
            As[kl*68 + row] = v;
        }
        __syncthreads();
        #pragma unroll
        for (int kk = 0; kk < 32; ++kk) {
            float4 w  = *(const float4*)&Ws[kk*132 + cg*4];
            float4 a0 = *(const float4*)&As[kk*68 + rg*8];
            float4 a1 = *(const float4*)&As[kk*68 + rg*8 + 4];
            FMA4(c[0], a0.x, w); FMA4(c[1], a0.y, w); FMA4(c[2], a0.z, w); FMA4(c[3], a0.w, w);
            FMA4(c[4], a1.x, w); FMA4(c[5], a1.y, w); FMA4(c[6], a1.z, w); FMA4(c[7], a1.w, w);
        }
        __syncthreads();
    }

    const float4 bj = *(const float4*)&bias[cg*4];

    if (EMODE == 5) {
        float4 s = make_float4(0.f,0.f,0.f,0.f);
        #pragma unroll
        for (int r = 0; r < 8; ++r) {
            int m = m0 + rg*8 + r;
            float nv = nbm[m];
            s.x += gelu1(c[r].x + bj.x) * nv;
            s.y += gelu1(c[r].y + bj.y) * nv;
            s.z += gelu1(c[r].z + bj.z) * nv;
            s.w += gelu1(c[r].w + bj.w) * nv;
        }
        *(float4*)&C[(size_t)(m0/8 + rg)*128 + cg*4] = s;
        return;
    }

    #pragma unroll
    for (int r = 0; r < 8; ++r) {
        int m = m0 + rg*8 + r;
        float4 v = make_float4(c[r].x + bj.x, c[r].y + bj.y, c[r].z + bj.z, c[r].w + bj.w);
        if (EMODE == 1) {
            v.x = gelu1(v.x); v.y = gelu1(v.y); v.z = gelu1(v.z); v.w = gelu1(v.w);
        } else if (EMODE == 2) {
            v.x = tanhf(v.x); v.y = tanhf(v.y); v.z = tanhf(v.z); v.w = tanhf(v.w);
        } else if (EMODE == 3) {
            float4 e = *(const float4*)&extraM[(size_t)m*128 + cg*4];
            v.x = p0*v.x + p1*e.x; v.y = p0*v.y + p1*e.y; v.z = p0*v.z + p1*e.z; v.w = p0*v.w + p1*e.w;
        } else if (EMODE == 4) {
            int b = m / rowsPerB;
            float4 eb = *(const float4*)&extraB [(size_t)b*128 + cg*4];
            float4 e2 = *(const float4*)&extraB2[(size_t)b*128 + cg*4];
            float4 em = *(const float4*)&extraM [(size_t)m*128 + cg*4];
            float zx = sig1(v.x + eb.x), zy = sig1(v.y + eb.y), zz = sig1(v.z + eb.z), zw = sig1(v.w + eb.w);
            v.x = (1.f-zx)*em.x + zx*e2.x; v.y = (1.f-zy)*em.y + zy*e2.y;
            v.z = (1.f-zz)*em.z + zz*e2.z; v.w = (1.f-zw)*em.w + zw*e2.w;
        }
        *(float4*)&C[(size_t)m*128 + cg*4] = v;
        if (EMODE == 1 && C2 != nullptr) *(float4*)&C2[(size_t)m*128 + cg*4] = v;
    }
}

// ---------------------------------------------------------------------------
// Fused GRU cell: out = GRU(x, h) with pre-transposed weights WT [128,384]
// block = 256 threads, 32 rows per block
// ---------------------------------------------------------------------------
__global__ __launch_bounds__(256) void gru_kernel(
    const float* __restrict__ x, const float* __restrict__ h, float* __restrict__ out,
    const float* __restrict__ WTih, const float* __restrict__ WThh,
    const float* __restrict__ bih, const float* __restrict__ bhh)
{
    __shared__ __align__(16) float xs[32*132];
    __shared__ __align__(16) float hs[32*132];
    __shared__ __align__(16) float ws[32*132];
    const int t = threadIdx.x;
    const size_t m0 = (size_t)blockIdx.x * 32;
    #pragma unroll
    for (int it = 0; it < 16; ++it) {
        int id = it*256 + t; int row = id >> 7; int col = id & 127;
        xs[row*132 + col] = x[(m0+row)*128 + col];
        hs[row*132 + col] = h[(m0+row)*128 + col];
    }
    __syncthreads();
    const int rg = t >> 5, cg = t & 31;

    auto pass = [&](const float* src, const float* WT, int g, float4* acc) {
        for (int kc = 0; kc < 4; ++kc) {
            __syncthreads();
            #pragma unroll
            for (int it = 0; it < 16; ++it) {
                int id = it*256 + t; int kk = id >> 7; int col = id & 127;
                ws[kk*132 + col] = WT[(size_t)(kc*32+kk)*384 + g*128 + col];
            }
            __syncthreads();
            #pragma unroll
            for (int kk = 0; kk < 32; ++kk) {
                float4 w = *(const float4*)&ws[kk*132 + cg*4];
                #pragma unroll
                for (int r = 0; r < 4; ++r) {
                    float a = src[(rg*4+r)*132 + kc*32 + kk];
                    FMA4(acc[r], a, w);
                }
            }
        }
    };

    float4 rr[4], zz[4], ax[4], ah[4];
    float4 b1, b2;
    // r gate
    b1 = *(const float4*)&bih[0*128 + cg*4]; b2 = *(const float4*)&bhh[0*128 + cg*4];
    #pragma unroll
    for (int r = 0; r < 4; ++r) rr[r] = make_float4(b1.x+b2.x, b1.y+b2.y, b1.z+b2.z, b1.w+b2.w);
    pass(xs, WTih, 0, rr); pass(hs, WThh, 0, rr);
    #pragma unroll
    for (int r = 0; r < 4; ++r) { rr[r].x=sig1(rr[r].x); rr[r].y=sig1(rr[r].y); rr[r].z=sig1(rr[r].z); rr[r].w=sig1(rr[r].w); }
    // z gate
    b1 = *(const float4*)&bih[1*128 + cg*4]; b2 = *(const float4*)&bhh[1*128 + cg*4];
    #pragma unroll
    for (int r = 0; r < 4; ++r) zz[r] = make_float4(b1.x+b2.x, b1.y+b2.y, b1.z+b2.z, b1.w+b2.w);
    pass(xs, WTih, 1, zz); pass(hs, WThh, 1, zz);
    #pragma unroll
    for (int r = 0; r < 4; ++r) { zz[r].x=sig1(zz[r].x); zz[r].y=sig1(zz[r].y); zz[r].z=sig1(zz[r].z); zz[r].w=sig1(zz[r].w); }
    // n gate (x part and h part separate: n = tanh(inn + r*hn))
    b1 = *(const float4*)&bih[2*128 + cg*4]; b2 = *(const float4*)&bhh[2*128 + cg*4];
    #pragma unroll
    for (int r = 0; r < 4; ++r) { ax[r] = make_float4(b1.x,b1.y,b1.z,b1.w); ah[r] = make_float4(b2.x,b2.y,b2.z,b2.w); }
    pass(xs, WTih, 2, ax); pass(hs, WThh, 2, ah);

    #pragma unroll
    for (int r = 0; r < 4; ++r) {
        int row = rg*4 + r;
        float4 hv = *(const float4*)&hs[row*132 + cg*4];
        float nx = tanhf(ax[r].x + rr[r].x*ah[r].x);
        float ny = tanhf(ax[r].y + rr[r].y*ah[r].y);
        float nz = tanhf(ax[r].z + rr[r].z*ah[r].z);
        float nw = tanhf(ax[r].w + rr[r].w*ah[r].w);
        float4 o;
        o.x = (1.f-zz[r].x)*nx + zz[r].x*hv.x;
        o.y = (1.f-zz[r].y)*ny + zz[r].y*hv.y;
        o.z = (1.f-zz[r].z)*nz + zz[r].z*hv.z;
        o.w = (1.f-zz[r].w)*nw + zz[r].w*hv.w;
        *(float4*)&out[(m0+row)*128 + cg*4] = o;
    }
}

// ---------------------------------------------------------------------------
// small helper kernels
// ---------------------------------------------------------------------------
__global__ void transpose384_kernel(const float* __restrict__ src, float* __restrict__ dst)
{
    int o = blockIdx.x*256 + threadIdx.x;   // dst[k*384+j] = src[j*128+k], o < 49152
    if (o >= 49152) return;
    int k = o / 384, j = o - k*384;
    dst[o] = src[j*128 + k];
}

__global__ void e_gather_kernel(const float* __restrict__ bondf, const int* __restrict__ edge,
                                float* __restrict__ e_init)
{
    int idx = blockIdx.x*256 + threadIdx.x;  // < B*E*6
    if (idx >= BB*EE*BF) return;
    int m = idx / BF, j = idx - m*BF;
    e_init[idx] = bondf[edge[m]*BF + j];
}

__global__ __launch_bounds__(256) void master_init_kernel(const float* __restrict__ vf,
                                                          const float* __restrict__ vm,
                                                          float* __restrict__ master)
{
    __shared__ float red[256];
    int b = blockIdx.x; int t = threadIdx.x; int hcol = t & 127; int half = t >> 7;
    float s = 0.f;
    for (int n = half; n < NN; n += 2)
        s += vf[((size_t)b*NN + n)*HH + hcol] * vm[b*NN + n];
    red[t] = s; __syncthreads();
    if (half == 0) master[b*HH + hcol] = red[hcol] + red[hcol + 128];
}

// score[b,k,n] = sum_d tanh_mv[b,k,n,d]*master[b,d]*wbmm_w[k,d] + wbmm_b[k]
__global__ __launch_bounds__(256) void score_kernel(const float* __restrict__ S,
                                                    const float* __restrict__ master,
                                                    const float* __restrict__ wbw,
                                                    const float* __restrict__ wbb,
                                                    float* __restrict__ score)
{
    int w = threadIdx.x >> 6; int lane = threadIdx.x & 63;
    int row = blockIdx.x*4 + w;            // < B*K*N
    int b = row >> 11;                     // K*N = 2048
    int k = (row >> 9) & 3;
    int n = row & 511;
    const float* srow = S + (size_t)k*SLAB + ((size_t)b*NN + n)*HH;
    const float* mrow = master + b*HH;
    const float* wk   = wbw + k*HH;
    float p = srow[lane]*mrow[lane]*wk[lane] + srow[lane+64]*mrow[lane+64]*wk[lane+64];
    #pragma unroll
    for (int off = 32; off; off >>= 1) p += __shfl_down(p, off);
    if (lane == 0) score[row] = p + wbb[k];
}

__global__ __launch_bounds__(256) void softmax_kernel(float* __restrict__ att,
                                                      const float* __restrict__ vm)
{
    __shared__ float red[256];
    int t = threadIdx.x;
    int bk = blockIdx.x; int b = bk >> 2;
    float* a = att + (size_t)bk*NN;
    float v0 = a[t], v1 = a[t+256];
    red[t] = fmaxf(v0, v1); __syncthreads();
    for (int s = 128; s; s >>= 1) { if (t < s) red[t] = fmaxf(red[t], red[t+s]); __syncthreads(); }
    float mx = red[0]; __syncthreads();
    float e0 = expf(v0 - mx) * vm[b*NN + t];
    float e1 = expf(v1 - mx) * vm[b*NN + t + 256];
    red[t] = e0 + e1; __syncthreads();
    for (int s = 128; s; s >>= 1) { if (t < s) red[t] += red[t+s]; __syncthreads(); }
    float inv = 1.f / (red[0] + 1e-6f);
    a[t] = e0*inv; a[t+256] = e1*inv;
}

// kmm[b,k,d] = sum_n att[b,k,n]*proj[b,k,n,d]
__global__ __launch_bounds__(128) void kmm_kernel(const float* __restrict__ S,
                                                  const float* __restrict__ att,
                                                  float* __restrict__ kmm)
{
    int b = blockIdx.x >> 2, k = blockIdx.x & 3;
    int d = threadIdx.x;
    const float* at = att + ((size_t)b*KK + k)*NN;
    const float* Sk = S + (size_t)k*SLAB + (size_t)b*NN*HH;
    float acc = 0.f;
    for (int n = 0; n < NN; ++n) acc += at[n] * Sk[(size_t)n*HH + d];
    kmm[((size_t)b*KK + k)*HH + d] = acc;
}

__global__ void pw_support_kernel(float* __restrict__ hi, const float* __restrict__ h0)
{
    int i = blockIdx.x*256 + threadIdx.x;           // float4 index, total 1048576
    float4 a = ((const float4*)hi)[i];
    float4 b = ((const float4*)h0)[i];
    a.x = 0.9f*a.x + 0.1f*b.x; a.y = 0.9f*a.y + 0.1f*b.y;
    a.z = 0.9f*a.z + 0.1f*b.z; a.w = 0.9f*a.w + 0.1f*b.w;
    ((float4*)hi)[i] = a;
}

__global__ void pw_hsup_kernel(const float* __restrict__ ts1, const float* __restrict__ ts2,
                               const float* __restrict__ mself, const float* __restrict__ mtm,
                               float* __restrict__ hsup)
{
    int i = blockIdx.x*256 + threadIdx.x;  // < B*H
    if (i >= BB*HH) return;
    float z = sig1(ts1[i] + ts2[i]);
    hsup[i] = (1.f-z)*mself[i] + z*mtm[i];
}

__global__ void copy_out_kernel(const float* __restrict__ vf, const float* __restrict__ master,
                                float* __restrict__ out)
{
    int i = blockIdx.x*256 + threadIdx.x;   // float4 index, total (4194304+8192)/4
    const int nvf4 = SLAB/4;
    if (i < nvf4) ((float4*)out)[i] = ((const float4*)vf)[i];
    else ((float4*)out)[i] = ((const float4*)master)[i - nvf4];
}

// ---------------------------------------------------------------------------
extern "C" void kernel_launch(void* const* d_in, const int* in_sizes, int n_in,
                              void* d_out, int out_size, void* d_ws, size_t ws_size,
                              hipStream_t stream)
{
    (void)in_sizes; (void)n_in; (void)out_size; (void)ws_size;
    const float* vmask = (const float*)d_in[1];
    const int*   vertex= (const int*)d_in[2];
    const int*   edge  = (const int*)d_in[3];
    const int*   aadj  = (const int*)d_in[4];
    const int*   badj  = (const int*)d_in[5];
    const float* nbm   = (const float*)d_in[6];
    const float* atomf = (const float*)d_in[7];
    const float* bondf = (const float*)d_in[8];
    const float* emb_w = (const float*)d_in[9];
    const float* emb_b = (const float*)d_in[10];
    const float* u1_w  = (const float*)d_in[11];
    const float* u1_b  = (const float*)d_in[12];
    const float* u2_w  = (const float*)d_in[13];
    const float* u2_b  = (const float*)d_in[14];
    const float* fu_w  = (const float*)d_in[15];
    const float* fu_b  = (const float*)d_in[16];
    const float* wvm_w = (const float*)d_in[17];
    const float* wvm_b = (const float*)d_in[18];
    const float* wmain_w=(const float*)d_in[19];
    const float* wmain_b=(const float*)d_in[20];
    const float* wbmm_w= (const float*)d_in[21];
    const float* wbmm_b= (const float*)d_in[22];
    const float* khead_w=(const float*)d_in[23];
    const float* khead_b=(const float*)d_in[24];
    const float* wmaster_w=(const float*)d_in[25];
    const float* wmaster_b=(const float*)d_in[26];
    const float* wm2m_w= (const float*)d_in[27];
    const float* wm2m_b= (const float*)d_in[28];
    const float* wzm1_w= (const float*)d_in[29];
    const float* wzm1_b= (const float*)d_in[30];
    const float* wzm2_w= (const float*)d_in[31];
    const float* wzm2_b= (const float*)d_in[32];
    const float* wzs1_w= (const float*)d_in[33];
    const float* wzs1_b= (const float*)d_in[34];
    const float* wzs2_w= (const float*)d_in[35];
    const float* wzs2_b= (const float*)d_in[36];
    const float* g_wih = (const float*)d_in[37];
    const float* g_whh = (const float*)d_in[38];
    const float* g_bih = (const float*)d_in[39];
    const float* g_bhh = (const float*)d_in[40];
    const float* gm_wih= (const float*)d_in[41];
    const float* gm_whh= (const float*)d_in[42];
    const float* gm_bih= (const float*)d_in[43];
    const float* gm_bhh= (const float*)d_in[44];

    float* ws     = (float*)d_ws;
    float* vf     = ws;
    float* h0     = vf + SLAB;
    float* S      = h0 + SLAB;            // 4 slabs
    float* e_init = S + 4*(size_t)SLAB;
    float* att    = e_init + BB*EE*BF;
    float* kmm    = att + BB*KK*NN;
    float* master = kmm + BB*KK*HH;
    float* m2m    = master + BB*HH;
    float* mself  = m2m + BB*HH;
    float* t2     = mself + BB*HH;
    float* mtm    = t2 + BB*HH;
    float* ts1    = mtm + BB*HH;
    float* ts2    = ts1 + BB*HH;
    float* hsup   = ts2 + BB*HH;
    float* WTih_m = hsup + BB*HH;
    float* WThh_m = WTih_m + 128*384;
    float* WTih_s = WThh_m + 128*384;
    float* WThh_s = WTih_s + 128*384;

    const float* NPF = nullptr;
    const int*   NPI = nullptr;
    float*       NPW = nullptr;

    // one-time (per launch) weight transposes for GRU
    transpose384_kernel<<<192, 256, 0, stream>>>(g_wih,  WTih_m);
    transpose384_kernel<<<192, 256, 0, stream>>>(g_whh,  WThh_m);
    transpose384_kernel<<<192, 256, 0, stream>>>(gm_wih, WTih_s);
    transpose384_kernel<<<192, 256, 0, stream>>>(gm_whh, WThh_s);

    // e_init gather
    e_gather_kernel<<<(BB*EE*BF + 255)/256, 256, 0, stream>>>(bondf, edge, e_init);

    // embed: vf = gelu((atomf[vertex]*vm) @ emb_w + emb_b), dual-store into h0
    gemm_kernel<1,1><<<dim3(512,1,1), 256, 0, stream>>>(
        atomf, NPF, emb_w, emb_b, vf, h0, BB*NN, AF,
        vertex, NPI, vmask, NPF, NPF, NPF, NPF, 0.f, 0.f, 1, 0ULL);

    master_init_kernel<<<BB, 256, 0, stream>>>(vf, vmask, master);

    for (int i = 0; i < LL; ++i) {
        float theta = logf(0.5f/(float)(i+1) + 1.f);
        const float* wvmW = wvm_w + (size_t)i*KK*HH*HH;
        const float* wvmB = wvm_b + (size_t)i*KK*HH;
        const float* wmnW = wmain_w + (size_t)i*KK*HH*HH;
        const float* wmnB = wmain_b + (size_t)i*KK*HH;

        // mv = tanh(vf @ wvm_w[i,k] + b)   -> S[k]
        gemm_kernel<0,2><<<dim3(512,1,4), 256, 0, stream>>>(
            vf, NPF, wvmW, wvmB, S, NPW, BB*NN, HH,
            NPI, NPI, NPF, NPF, NPF, NPF, NPF, 0.f, 0.f, 1, (unsigned long long)SLAB);
        // score
        score_kernel<<<BB*KK*NN/4, 256, 0, stream>>>(S, master, wbmm_w + i*KK*HH, wbmm_b + i*KK, att);
        // softmax over n
        softmax_kernel<<<BB*KK, 256, 0, stream>>>(att, vmask);
        // proj = vf @ wmain_w[i,k] + b -> S[k]
        gemm_kernel<0,0><<<dim3(512,1,4), 256, 0, stream>>>(
            vf, NPF, wmnW, wmnB, S, NPW, BB*NN, HH,
            NPI, NPI, NPF, NPF, NPF, NPF, NPF, 0.f, 0.f, 1, (unsigned long long)SLAB);
        // kmm
        kmm_kernel<<<BB*KK, 128, 0, stream>>>(S, att, kmm);
        // main_to_master = tanh(kmm @ khead_w[i] + b)
        gemm_kernel<0,2><<<dim3(1,1,1), 256, 0, stream>>>(
            kmm, NPF, khead_w + (size_t)i*KK*HH*HH, khead_b + i*HH, mtm, NPW, BB, KK*HH,
            NPI, NPI, NPF, NPF, NPF, NPF, NPF, 0.f, 0.f, 1, 0ULL);
        // u1: nl = sum_s gelu(concat(vf[aa], e_init[ba]) @ u1_w + b) * nbm  -> S0
        gemm_kernel<3,5><<<dim3(4096,1,1), 256, 0, stream>>>(
            vf, e_init, u1_w + (size_t)i*(HH+BF)*HH, u1_b + i*HH, S, NPW, BB*NN*NBS, HH+BF,
            aadj, badj, NPF, nbm, NPF, NPF, NPF, 0.f, 0.f, 1, 0ULL);
        // u2: hi = concat(nl, vf) @ u2_w + b -> S1
        gemm_kernel<2,0><<<dim3(512,1,1), 256, 0, stream>>>(
            S, vf, u2_w + (size_t)i*2*HH*HH, u2_b + i*HH, S + SLAB, NPW, BB*NN, 2*HH,
            NPI, NPI, NPF, NPF, NPF, NPF, NPF, 0.f, 0.f, 1, 0ULL);
        // support = 0.9*hi + 0.1*h0  (in place S1)
        pw_support_kernel<<<4096, 256, 0, stream>>>(S + SLAB, h0);
        // self_vertex = theta*(support@fu+b) + (1-theta)*support -> S2
        gemm_kernel<0,3><<<dim3(512,1,1), 256, 0, stream>>>(
            S + SLAB, NPF, fu_w + (size_t)i*HH*HH, fu_b + i*HH, S + 2*(size_t)SLAB, NPW, BB*NN, HH,
            NPI, NPI, NPF, NPF, S + SLAB, NPF, NPF, theta, 1.f - theta, 1, 0ULL);
        // m2m = gelu(master @ wm2m + b); mself = gelu(master @ wmaster + b)
        gemm_kernel<0,1><<<dim3(1,1,1), 256, 0, stream>>>(
            master, NPF, wm2m_w + (size_t)i*HH*HH, wm2m_b + i*HH, m2m, NPW, BB, HH,
            NPI, NPI, NPF, NPF, NPF, NPF, NPF, 0.f, 0.f, 1, 0ULL);
        gemm_kernel<0,1><<<dim3(1,1,1), 256, 0, stream>>>(
            master, NPF, wmaster_w + (size_t)i*HH*HH, wmaster_b + i*HH, mself, NPW, BB, HH,
            NPI, NPI, NPF, NPF, NPF, NPF, NPF, 0.f, 0.f, 1, 0ULL);
        // t2 = m2m @ wzm2 + b
        gemm_kernel<0,0><<<dim3(1,1,1), 256, 0, stream>>>(
            m2m, NPF, wzm2_w + (size_t)i*HH*HH, wzm2_b + i*HH, t2, NPW, BB, HH,
            NPI, NPI, NPF, NPF, NPF, NPF, NPF, 0.f, 0.f, 1, 0ULL);
        // z_main gate fused: hidden_main = (1-z)*sv + z*m2m, z = sig(sv@wzm1+b + t2[b]) -> S3
        gemm_kernel<0,4><<<dim3(512,1,1), 256, 0, stream>>>(
            S + 2*(size_t)SLAB, NPF, wzm1_w + (size_t)i*HH*HH, wzm1_b + i*HH, S + 3*(size_t)SLAB, NPW, BB*NN, HH,
            NPI, NPI, NPF, NPF, S + 2*(size_t)SLAB, t2, m2m, 0.f, 0.f, NN, 0ULL);
        // vf = GRU(hidden_main, vf)
        gru_kernel<<<BB*NN/32, 256, 0, stream>>>(S + 3*(size_t)SLAB, vf, vf, WTih_m, WThh_m, g_bih, g_bhh);
        // master path
        gemm_kernel<0,0><<<dim3(1,1,1), 256, 0, stream>>>(
            mself, NPF, wzs1_w + (size_t)i*HH*HH, wzs1_b + i*HH, ts1, NPW, BB, HH,
            NPI, NPI, NPF, NPF, NPF, NPF, NPF, 0.f, 0.f, 1, 0ULL);
        gemm_kernel<0,0><<<dim3(1,1,1), 256, 0, stream>>>(
            mtm, NPF, wzs2_w + (size_t)i*HH*HH, wzs2_b + i*HH, ts2, NPW, BB, HH,
            NPI, NPI, NPF, NPF, NPF, NPF, NPF, 0.f, 0.f, 1, 0ULL);
        pw_hsup_kernel<<<(BB*HH + 255)/256, 256, 0, stream>>>(ts1, ts2, mself, mtm, hsup);
        // master = GRU(hidden_super, master)
        gru_kernel<<<BB/32, 256, 0, stream>>>(hsup, master, master, WTih_s, WThh_s, gm_bih, gm_bhh);
    }

    copy_out_kernel<<<(SLAB + BB*HH)/4/256, 256, 0, stream>>>(vf, master, (float*)d_out);
}

// Round 3
// 3389.051 us; speedup vs baseline: 1.2775x; 1.2775x over previous
//
#include <hip/hip_runtime.h>
#include <hip/hip_bf16.h>
#include <cmath>

// Problem constants
#define BB 64
#define NN 512
#define NBS 8
#define EE 2048
#define HH 128
#define LL 3
#define KK 4
#define AF 82
#define BF 6
#define SLAB 4194304   // B*N*H floats

typedef __attribute__((ext_vector_type(8))) short bf16x8;
typedef __attribute__((ext_vector_type(4))) float f32x4;

__device__ __forceinline__ float gelu1(float x){ return 0.5f*x*(1.f+erff(x*0.7071067811865475f)); }
__device__ __forceinline__ float sig1(float x){ return 1.f/(1.f+expf(-x)); }
__device__ __forceinline__ short f2bs(float x){ __hip_bfloat16 b=__float2bfloat16(x); return *reinterpret_cast<short*>(&b); }
__device__ __forceinline__ float bs2f(short s){ unsigned u = ((unsigned)(unsigned short)s) << 16; union{unsigned u; float f;} c; c.u=u; return c.f; }
__device__ __forceinline__ void split2(float v, short& hi, short& lo){ hi = f2bs(v); lo = f2bs(v - bs2f(hi)); }

#define FMA4(acc, a, w) { (acc).x += (a)*(w).x; (acc).y += (a)*(w).y; (acc).z += (a)*(w).z; (acc).w += (a)*(w).w; }

// ---------------------------------------------------------------------------
// Split-bf16 (emulated fp32) MFMA GEMM: C[M,128] = epi(A[M,K] @ W[K,128] + b)
// Weight tables: hi at WT[col*Kpad+k], lo at WT[loOff + col*Kpad+k].
// acc += a_hi*w_hi + a_lo*w_hi + a_hi*w_lo  (rel err ~2^-17)
// AMODE: 0 contiguous fp32 A; 1 atom-gather*vmask; 2 concat(A,A2); 3 u1 gather
// EMODE: 0 bias; 1 gelu(+C2); 2 tanh; 3 theta-blend; 4 z-gate; 5 u1 segsum
// ---------------------------------------------------------------------------
template<int AMODE, int EMODE>
__global__ __launch_bounds__(256) void mgemm(
    const float* __restrict__ A, const float* __restrict__ A2,
    const short* __restrict__ WT, const float* __restrict__ bias,
    float* __restrict__ C, float* __restrict__ C2,
    int K, int Kpad,
    const int* __restrict__ g1, const int* __restrict__ g2,
    const float* __restrict__ vmask, const float* __restrict__ nbm,
    const float* __restrict__ extraM, const float* __restrict__ extraB,
    const float* __restrict__ extraB2,
    float p0, float p1, int rowsPerB,
    unsigned long long zCs, unsigned long long zWs, unsigned long long loOff)
{
    const int t = threadIdx.x;
    const int lane = t & 63, wv = t >> 6;
    const int quad = lane >> 4, ml = lane & 15;
    const int z = blockIdx.z;
    const short* WTz = WT + (size_t)z * zWs;
    const float* bz  = bias + (size_t)z * 128;
    float* Cz        = C + (size_t)z * zCs;
    const int m0 = blockIdx.x * 128 + wv * 32;

    const int r0 = m0 + ml, r1 = m0 + 16 + ml;
    int ga0 = 0, ga1 = 0, gb0 = 0, gb1 = 0; float vm0 = 0.f, vm1 = 0.f;
    if (AMODE == 1) { ga0 = g1[r0]; ga1 = g1[r1]; vm0 = vmask[r0]; vm1 = vmask[r1]; }
    if (AMODE == 3) { ga0 = g1[r0]; ga1 = g1[r1]; gb0 = g2[r0]; gb1 = g2[r1]; }

    f32x4 acc[16];
    #pragma unroll
    for (int i = 0; i < 16; ++i) acc[i] = (f32x4){0.f,0.f,0.f,0.f};

    const int nchunk = Kpad >> 5;
    const short* wcol = WTz + (size_t)ml * Kpad;

    for (int kc = 0; kc < nchunk; ++kc) {
        const int kq = kc*32 + quad*8;
        float av0[8], av1[8];
        if (AMODE == 0) {
            const float* p0r = A + (size_t)r0*K + kq;
            const float* p1r = A + (size_t)r1*K + kq;
            float4 a0 = *(const float4*)p0r, a1 = *(const float4*)(p0r+4);
            float4 b0 = *(const float4*)p1r, b1 = *(const float4*)(p1r+4);
            av0[0]=a0.x; av0[1]=a0.y; av0[2]=a0.z; av0[3]=a0.w;
            av0[4]=a1.x; av0[5]=a1.y; av0[6]=a1.z; av0[7]=a1.w;
            av1[0]=b0.x; av1[1]=b0.y; av1[2]=b0.z; av1[3]=b0.w;
            av1[4]=b1.x; av1[5]=b1.y; av1[6]=b1.z; av1[7]=b1.w;
        } else if (AMODE == 1) {
            const float* p0r = A + (size_t)ga0*K + kq;
            const float* p1r = A + (size_t)ga1*K + kq;
            #pragma unroll
            for (int j2 = 0; j2 < 4; ++j2) {
                int k = kq + 2*j2;
                if (k + 2 <= K) {
                    float2 v0 = *(const float2*)(p0r + 2*j2);
                    float2 v1 = *(const float2*)(p1r + 2*j2);
                    av0[2*j2]=v0.x*vm0; av0[2*j2+1]=v0.y*vm0;
                    av1[2*j2]=v1.x*vm1; av1[2*j2+1]=v1.y*vm1;
                } else { av0[2*j2]=0.f; av0[2*j2+1]=0.f; av1[2*j2]=0.f; av1[2*j2+1]=0.f; }
            }
        } else if (AMODE == 2) {
            const float* p0r = (kq < 128) ? A + (size_t)r0*128 + kq : A2 + (size_t)r0*128 + (kq-128);
            const float* p1r = (kq < 128) ? A + (size_t)r1*128 + kq : A2 + (size_t)r1*128 + (kq-128);
            float4 a0 = *(const float4*)p0r, a1 = *(const float4*)(p0r+4);
            float4 b0 = *(const float4*)p1r, b1 = *(const float4*)(p1r+4);
            av0[0]=a0.x; av0[1]=a0.y; av0[2]=a0.z; av0[3]=a0.w;
            av0[4]=a1.x; av0[5]=a1.y; av0[6]=a1.z; av0[7]=a1.w;
            av1[0]=b0.x; av1[1]=b0.y; av1[2]=b0.z; av1[3]=b0.w;
            av1[4]=b1.x; av1[5]=b1.y; av1[6]=b1.z; av1[7]=b1.w;
        } else { // AMODE 3
            if (kq < 128) {
                const float* p0r = A + (size_t)ga0*128 + kq;
                const float* p1r = A + (size_t)ga1*128 + kq;
                float4 a0 = *(const float4*)p0r, a1 = *(const float4*)(p0r+4);
                float4 b0 = *(const float4*)p1r, b1 = *(const float4*)(p1r+4);
                av0[0]=a0.x; av0[1]=a0.y; av0[2]=a0.z; av0[3]=a0.w;
                av0[4]=a1.x; av0[5]=a1.y; av0[6]=a1.z; av0[7]=a1.w;
                av1[0]=b0.x; av1[1]=b0.y; av1[2]=b0.z; av1[3]=b0.w;
                av1[4]=b1.x; av1[5]=b1.y; av1[6]=b1.z; av1[7]=b1.w;
            } else if (kq == 128) {
                const float* p0r = A2 + (size_t)gb0*6;
                const float* p1r = A2 + (size_t)gb1*6;
                float2 x0=*(const float2*)p0r, x1=*(const float2*)(p0r+2), x2=*(const float2*)(p0r+4);
                float2 y0=*(const float2*)p1r, y1=*(const float2*)(p1r+2), y2=*(const float2*)(p1r+4);
                av0[0]=x0.x; av0[1]=x0.y; av0[2]=x1.x; av0[3]=x1.y; av0[4]=x2.x; av0[5]=x2.y; av0[6]=0.f; av0[7]=0.f;
                av1[0]=y0.x; av1[1]=y0.y; av1[2]=y1.x; av1[3]=y1.y; av1[4]=y2.x; av1[5]=y2.y; av1[6]=0.f; av1[7]=0.f;
            } else {
                #pragma unroll
                for (int j = 0; j < 8; ++j) { av0[j]=0.f; av1[j]=0.f; }
            }
        }
        bf16x8 a0h, a0l, a1h, a1l;
        #pragma unroll
        for (int j = 0; j < 8; ++j) {
            short h, l;
            split2(av0[j], h, l); a0h[j]=h; a0l[j]=l;
            split2(av1[j], h, l); a1h[j]=h; a1l[j]=l;
        }

        #pragma unroll
        for (int nt = 0; nt < 8; ++nt) {
            const short* bp = wcol + (size_t)nt*16*Kpad + kq;
            bf16x8 bh = *(const bf16x8*)bp;
            bf16x8 bl = *(const bf16x8*)(bp + loOff);
            acc[nt] = __builtin_amdgcn_mfma_f32_16x16x32_bf16(a0h, bh, acc[nt], 0,0,0);
            acc[nt] = __builtin_amdgcn_mfma_f32_16x16x32_bf16(a0l, bh, acc[nt], 0,0,0);
            acc[nt] = __builtin_amdgcn_mfma_f32_16x16x32_bf16(a0h, bl, acc[nt], 0,0,0);
            acc[8+nt] = __builtin_amdgcn_mfma_f32_16x16x32_bf16(a1h, bh, acc[8+nt], 0,0,0);
            acc[8+nt] = __builtin_amdgcn_mfma_f32_16x16x32_bf16(a1l, bh, acc[8+nt], 0,0,0);
            acc[8+nt] = __builtin_amdgcn_mfma_f32_16x16x32_bf16(a1h, bl, acc[8+nt], 0,0,0);
        }
    }

    // --- epilogue ---
    if constexpr (EMODE == 5) {
        __shared__ float red[4][16][132];
        #pragma unroll
        for (int mt = 0; mt < 2; ++mt) {
            __syncthreads();
            #pragma unroll
            for (int nt = 0; nt < 8; ++nt) {
                int col = nt*16 + ml;
                float bj = bz[col];
                #pragma unroll
                for (int r = 0; r < 4; ++r) {
                    int gm = m0 + mt*16 + quad*4 + r;
                    red[wv][quad*4+r][col] = gelu1(acc[mt*8+nt][r] + bj) * nbm[gm];
                }
            }
            __syncthreads();
            #pragma unroll
            for (int q = 0; q < 4; ++q) {
                int idx = lane*4 + q;
                int seg = idx >> 7, col = idx & 127;
                float s = 0.f;
                #pragma unroll
                for (int ss = 0; ss < 8; ++ss) s += red[wv][seg*8+ss][col];
                Cz[(size_t)(m0/8 + mt*2 + seg)*128 + col] = s;
            }
        }
        return;
    }

    #pragma unroll
    for (int mt = 0; mt < 2; ++mt) {
        #pragma unroll
        for (int nt = 0; nt < 8; ++nt) {
            int col = nt*16 + ml;
            float bj = bz[col];
            #pragma unroll
            for (int r = 0; r < 4; ++r) {
                int gm = m0 + mt*16 + quad*4 + r;
                float v = acc[mt*8+nt][r] + bj;
                if (EMODE == 1) v = gelu1(v);
                else if (EMODE == 2) v = tanhf(v);
                else if (EMODE == 3) v = p0*v + p1*extraM[(size_t)gm*128 + col];
                else if (EMODE == 4) {
                    int bi = gm / rowsPerB;
                    float zg = sig1(v + extraB[(size_t)bi*128 + col]);
                    v = (1.f-zg)*extraM[(size_t)gm*128 + col] + zg*extraB2[(size_t)bi*128 + col];
                }
                Cz[(size_t)gm*128 + col] = v;
                if (EMODE == 1 && C2 != nullptr) C2[(size_t)gm*128 + col] = v;
            }
        }
    }
}

// ---------------------------------------------------------------------------
// Fused GRU (main): gh = h @ whh^T via split-bf16 MFMA, combine with gi slabs,
// write vf in place. Each wave: 16 rows x 384 cols.
// ---------------------------------------------------------------------------
__global__ __launch_bounds__(256) void gru_mfma(
    const float* __restrict__ gi,   // 3 slabs of SLAB: r,z,n
    float* __restrict__ vf,
    const short* __restrict__ whh,  // [384][128] bf16, lo at +loOff
    const float* __restrict__ bhh,
    unsigned long long loOff)
{
    const int t = threadIdx.x;
    const int lane = t & 63, wv = t >> 6;
    const int quad = lane >> 4, ml = lane & 15;
    const int m0 = blockIdx.x * 64 + wv * 16;
    const int arow = m0 + ml;

    f32x4 acc[24];
    #pragma unroll
    for (int i = 0; i < 24; ++i) acc[i] = (f32x4){0.f,0.f,0.f,0.f};

    for (int kc = 0; kc < 4; ++kc) {
        const int kq = kc*32 + quad*8;
        const float* p = vf + (size_t)arow*128 + kq;
        float4 v0 = *(const float4*)p, v1 = *(const float4*)(p+4);
        float av[8] = {v0.x,v0.y,v0.z,v0.w,v1.x,v1.y,v1.z,v1.w};
        bf16x8 ah, al;
        #pragma unroll
        for (int j = 0; j < 8; ++j) { short h,l; split2(av[j],h,l); ah[j]=h; al[j]=l; }
        #pragma unroll
        for (int g = 0; g < 3; ++g) {
            #pragma unroll
            for (int nt = 0; nt < 8; ++nt) {
                const short* bp = whh + (size_t)(g*128 + nt*16 + ml)*128 + kq;
                bf16x8 bh = *(const bf16x8*)bp;
                bf16x8 bl = *(const bf16x8*)(bp + loOff);
                acc[g*8+nt] = __builtin_amdgcn_mfma_f32_16x16x32_bf16(ah, bh, acc[g*8+nt], 0,0,0);
                acc[g*8+nt] = __builtin_amdgcn_mfma_f32_16x16x32_bf16(al, bh, acc[g*8+nt], 0,0,0);
                acc[g*8+nt] = __builtin_amdgcn_mfma_f32_16x16x32_bf16(ah, bl, acc[g*8+nt], 0,0,0);
            }
        }
    }

    #pragma unroll
    for (int nt = 0; nt < 8; ++nt) {
        int col = nt*16 + ml;
        float br = bhh[col], bz2 = bhh[128+col], bn = bhh[256+col];
        #pragma unroll
        for (int r = 0; r < 4; ++r) {
            int gm = m0 + quad*4 + r;
            size_t off = (size_t)gm*128 + col;
            float gr = sig1(gi[off] + acc[nt][r] + br);
            float gz = sig1(gi[(size_t)SLAB + off] + acc[8+nt][r] + bz2);
            float gn = tanhf(gi[2ull*SLAB + off] + gr*(acc[16+nt][r] + bn));
            float hv = vf[off];
            vf[off] = (1.f-gz)*gn + gz*hv;
        }
    }
}

// ---------------------------------------------------------------------------
// Weight conversion: dst[i]=hi, dst[total+i]=lo
// Transposed: dst[z][col][k] from src[z][k][col], zero pad k>=K
__global__ void wcvt_t(const float* __restrict__ src, short* __restrict__ dst,
                       int K, int Kpad, int total)
{
    int i = blockIdx.x*256 + threadIdx.x;
    if (i >= total) return;
    int z = i / (128*Kpad); int rem = i - z*128*Kpad;
    int col = rem / Kpad; int k = rem - col*Kpad;
    float v = (k < K) ? src[(size_t)z*K*128 + (size_t)k*128 + col] : 0.f;
    short h, l; split2(v, h, l);
    dst[i] = h; dst[total + i] = l;
}

__global__ void wcvt_d(const float* __restrict__ src, short* __restrict__ dst, int n)
{
    int i = blockIdx.x*256 + threadIdx.x;
    if (i < n) { short h,l; split2(src[i], h, l); dst[i]=h; dst[n+i]=l; }
}

// ---------------------------------------------------------------------------
// fp32 GEMM kept for tiny master-path matmuls (M=64)
// ---------------------------------------------------------------------------
template<int AMODE, int EMODE>
__global__ __launch_bounds__(256) void gemm_kernel(
    const float* __restrict__ A, const float* __restrict__ A2,
    const float* __restrict__ W, const float* __restrict__ bias,
    float* __restrict__ C, float* __restrict__ C2,
    int M, int K,
    const int* __restrict__ g1, const int* __restrict__ g2,
    const float* __restrict__ vmask, const float* __restrict__ nbm,
    const float* __restrict__ extraM, const float* __restrict__ extraB,
    const float* __restrict__ extraB2,
    float p0, float p1, int rowsPerB, unsigned long long zCs)
{
    __shared__ __align__(16) float As[32*68];
    __shared__ __align__(16) float Ws[32*132];
    const int t  = threadIdx.x;
    const int m0 = blockIdx.x * 64;
    const int z  = blockIdx.z;
    W    += (size_t)z * K * 128;
    bias += (size_t)z * 128;
    C    += (size_t)z * zCs;

    const int rg = t >> 5;
    const int cg = t & 31;
    float4 c[8];
    #pragma unroll
    for (int r = 0; r < 8; ++r) c[r] = make_float4(0.f,0.f,0.f,0.f);

    const int nk = (K + 31) >> 5;
    for (int kc = 0; kc < nk; ++kc) {
        const int k0 = kc * 32;
        #pragma unroll
        for (int it = 0; it < 16; ++it) {
            int id = it*256 + t; int kk = id >> 7; int col = id & 127; int kg = k0 + kk;
            Ws[kk*132 + col] = (kg < K) ? W[(size_t)kg*128 + col] : 0.f;
        }
        #pragma unroll
        for (int it = 0; it < 8; ++it) {
            int id = it*256 + t; int kl = id & 31; int row = id >> 5; int kg = k0 + kl;
            float v = 0.f;
            if (AMODE == 0) { if (kg < K) v = A[(size_t)(m0+row)*K + kg]; }
            As[kl*68 + row] = v;
        }
        __syncthreads();
        #pragma unroll
        for (int kk = 0; kk < 32; ++kk) {
            float4 w  = *(const float4*)&Ws[kk*132 + cg*4];
            float4 a0 = *(const float4*)&As[kk*68 + rg*8];
            float4 a1 = *(const float4*)&As[kk*68 + rg*8 + 4];
            FMA4(c[0], a0.x, w); FMA4(c[1], a0.y, w); FMA4(c[2], a0.z, w); FMA4(c[3], a0.w, w);
            FMA4(c[4], a1.x, w); FMA4(c[5], a1.y, w); FMA4(c[6], a1.z, w); FMA4(c[7], a1.w, w);
        }
        __syncthreads();
    }

    const float4 bj = *(const float4*)&bias[cg*4];
    #pragma unroll
    for (int r = 0; r < 8; ++r) {
        int m = m0 + rg*8 + r;
        float4 v = make_float4(c[r].x + bj.x, c[r].y + bj.y, c[r].z + bj.z, c[r].w + bj.w);
        if (EMODE == 1) { v.x = gelu1(v.x); v.y = gelu1(v.y); v.z = gelu1(v.z); v.w = gelu1(v.w); }
        else if (EMODE == 2) { v.x = tanhf(v.x); v.y = tanhf(v.y); v.z = tanhf(v.z); v.w = tanhf(v.w); }
        *(float4*)&C[(size_t)m*128 + cg*4] = v;
        if (EMODE == 1 && C2 != nullptr) *(float4*)&C2[(size_t)m*128 + cg*4] = v;
    }
}

// ---------------------------------------------------------------------------
// GRU cell (fp32) kept for master (M=64)
// ---------------------------------------------------------------------------
__global__ __launch_bounds__(256) void gru_kernel(
    const float* __restrict__ x, const float* __restrict__ h, float* __restrict__ out,
    const float* __restrict__ WTih, const float* __restrict__ WThh,
    const float* __restrict__ bih, const float* __restrict__ bhh)
{
    __shared__ __align__(16) float xs[32*132];
    __shared__ __align__(16) float hs[32*132];
    __shared__ __align__(16) float ws[32*132];
    const int t = threadIdx.x;
    const size_t m0 = (size_t)blockIdx.x * 32;
    #pragma unroll
    for (int it = 0; it < 16; ++it) {
        int id = it*256 + t; int row = id >> 7; int col = id & 127;
        xs[row*132 + col] = x[(m0+row)*128 + col];
        hs[row*132 + col] = h[(m0+row)*128 + col];
    }
    __syncthreads();
    const int rg = t >> 5, cg = t & 31;

    auto pass = [&](const float* src, const float* WT, int g, float4* acc) {
        for (int kc = 0; kc < 4; ++kc) {
            __syncthreads();
            #pragma unroll
            for (int it = 0; it < 16; ++it) {
                int id = it*256 + t; int kk = id >> 7; int col = id & 127;
                ws[kk*132 + col] = WT[(size_t)(kc*32+kk)*384 + g*128 + col];
            }
            __syncthreads();
            #pragma unroll
            for (int kk = 0; kk < 32; ++kk) {
                float4 w = *(const float4*)&ws[kk*132 + cg*4];
                #pragma unroll
                for (int r = 0; r < 4; ++r) {
                    float a = src[(rg*4+r)*132 + kc*32 + kk];
                    FMA4(acc[r], a, w);
                }
            }
        }
    };

    float4 rr[4], zz[4], ax[4], ah[4];
    float4 b1, b2;
    b1 = *(const float4*)&bih[0*128 + cg*4]; b2 = *(const float4*)&bhh[0*128 + cg*4];
    #pragma unroll
    for (int r = 0; r < 4; ++r) rr[r] = make_float4(b1.x+b2.x, b1.y+b2.y, b1.z+b2.z, b1.w+b2.w);
    pass(xs, WTih, 0, rr); pass(hs, WThh, 0, rr);
    #pragma unroll
    for (int r = 0; r < 4; ++r) { rr[r].x=sig1(rr[r].x); rr[r].y=sig1(rr[r].y); rr[r].z=sig1(rr[r].z); rr[r].w=sig1(rr[r].w); }
    b1 = *(const float4*)&bih[1*128 + cg*4]; b2 = *(const float4*)&bhh[1*128 + cg*4];
    #pragma unroll
    for (int r = 0; r < 4; ++r) zz[r] = make_float4(b1.x+b2.x, b1.y+b2.y, b1.z+b2.z, b1.w+b2.w);
    pass(xs, WTih, 1, zz); pass(hs, WThh, 1, zz);
    #pragma unroll
    for (int r = 0; r < 4; ++r) { zz[r].x=sig1(zz[r].x); zz[r].y=sig1(zz[r].y); zz[r].z=sig1(zz[r].z); zz[r].w=sig1(zz[r].w); }
    b1 = *(const float4*)&bih[2*128 + cg*4]; b2 = *(const float4*)&bhh[2*128 + cg*4];
    #pragma unroll
    for (int r = 0; r < 4; ++r) { ax[r] = make_float4(b1.x,b1.y,b1.z,b1.w); ah[r] = make_float4(b2.x,b2.y,b2.z,b2.w); }
    pass(xs, WTih, 2, ax); pass(hs, WThh, 2, ah);

    #pragma unroll
    for (int r = 0; r < 4; ++r) {
        int row = rg*4 + r;
        float4 hv = *(const float4*)&hs[row*132 + cg*4];
        float nx = tanhf(ax[r].x + rr[r].x*ah[r].x);
        float ny = tanhf(ax[r].y + rr[r].y*ah[r].y);
        float nz = tanhf(ax[r].z + rr[r].z*ah[r].z);
        float nw = tanhf(ax[r].w + rr[r].w*ah[r].w);
        float4 o;
        o.x = (1.f-zz[r].x)*nx + zz[r].x*hv.x;
        o.y = (1.f-zz[r].y)*ny + zz[r].y*hv.y;
        o.z = (1.f-zz[r].z)*nz + zz[r].z*hv.z;
        o.w = (1.f-zz[r].w)*nw + zz[r].w*hv.w;
        *(float4*)&out[(m0+row)*128 + cg*4] = o;
    }
}

// ---------------------------------------------------------------------------
// small helper kernels
// ---------------------------------------------------------------------------
__global__ void transpose384_kernel(const float* __restrict__ src, float* __restrict__ dst)
{
    int o = blockIdx.x*256 + threadIdx.x;
    if (o >= 49152) return;
    int k = o / 384, j = o - k*384;
    dst[o] = src[j*128 + k];
}

__global__ void e_gather_kernel(const float* __restrict__ bondf, const int* __restrict__ edge,
                                float* __restrict__ e_init)
{
    int idx = blockIdx.x*256 + threadIdx.x;
    if (idx >= BB*EE*BF) return;
    int m = idx / BF, j = idx - m*BF;
    e_init[idx] = bondf[edge[m]*BF + j];
}

__global__ __launch_bounds__(256) void master_init_kernel(const float* __restrict__ vf,
                                                          const float* __restrict__ vm,
                                                          float* __restrict__ master)
{
    __shared__ float red[256];
    int b = blockIdx.x; int t = threadIdx.x; int hcol = t & 127; int half = t >> 7;
    float s = 0.f;
    for (int n = half; n < NN; n += 2)
        s += vf[((size_t)b*NN + n)*HH + hcol] * vm[b*NN + n];
    red[t] = s; __syncthreads();
    if (half == 0) master[b*HH + hcol] = red[hcol] + red[hcol + 128];
}

__global__ __launch_bounds__(256) void score_kernel(const float* __restrict__ S,
                                                    const float* __restrict__ master,
                                                    const float* __restrict__ wbw,
                                                    const float* __restrict__ wbb,
                                                    float* __restrict__ score)
{
    int w = threadIdx.x >> 6; int lane = threadIdx.x & 63;
    int row = blockIdx.x*4 + w;
    int b = row >> 11;
    int k = (row >> 9) & 3;
    int n = row & 511;
    const float* srow = S + (size_t)k*SLAB + ((size_t)b*NN + n)*HH;
    const float* mrow = master + b*HH;
    const float* wk   = wbw + k*HH;
    float p = srow[lane]*mrow[lane]*wk[lane] + srow[lane+64]*mrow[lane+64]*wk[lane+64];
    #pragma unroll
    for (int off = 32; off; off >>= 1) p += __shfl_down(p, off);
    if (lane == 0) score[row] = p + wbb[k];
}

__global__ __launch_bounds__(256) void softmax_kernel(float* __restrict__ att,
                                                      const float* __restrict__ vm)
{
    __shared__ float red[256];
    int t = threadIdx.x;
    int bk = blockIdx.x; int b = bk >> 2;
    float* a = att + (size_t)bk*NN;
    float v0 = a[t], v1 = a[t+256];
    red[t] = fmaxf(v0, v1); __syncthreads();
    for (int s = 128; s; s >>= 1) { if (t < s) red[t] = fmaxf(red[t], red[t+s]); __syncthreads(); }
    float mx = red[0]; __syncthreads();
    float e0 = expf(v0 - mx) * vm[b*NN + t];
    float e1 = expf(v1 - mx) * vm[b*NN + t + 256];
    red[t] = e0 + e1; __syncthreads();
    for (int s = 128; s; s >>= 1) { if (t < s) red[t] += red[t+s]; __syncthreads(); }
    float inv = 1.f / (red[0] + 1e-6f);
    a[t] = e0*inv; a[t+256] = e1*inv;
}

__global__ __launch_bounds__(128) void kmm_kernel(const float* __restrict__ S,
                                                  const float* __restrict__ att,
                                                  float* __restrict__ kmm)
{
    int b = blockIdx.x >> 2, k = blockIdx.x & 3;
    int d = threadIdx.x;
    const float* at = att + ((size_t)b*KK + k)*NN;
    const float* Sk = S + (size_t)k*SLAB + (size_t)b*NN*HH;
    float acc = 0.f;
    for (int n = 0; n < NN; ++n) acc += at[n] * Sk[(size_t)n*HH + d];
    kmm[((size_t)b*KK + k)*HH + d] = acc;
}

__global__ void pw_support_kernel(float* __restrict__ hi, const float* __restrict__ h0)
{
    int i = blockIdx.x*256 + threadIdx.x;
    float4 a = ((const float4*)hi)[i];
    float4 b = ((const float4*)h0)[i];
    a.x = 0.9f*a.x + 0.1f*b.x; a.y = 0.9f*a.y + 0.1f*b.y;
    a.z = 0.9f*a.z + 0.1f*b.z; a.w = 0.9f*a.w + 0.1f*b.w;
    ((float4*)hi)[i] = a;
}

__global__ void pw_hsup_kernel(const float* __restrict__ ts1, const float* __restrict__ ts2,
                               const float* __restrict__ mself, const float* __restrict__ mtm,
                               float* __restrict__ hsup)
{
    int i = blockIdx.x*256 + threadIdx.x;
    if (i >= BB*HH) return;
    float z = sig1(ts1[i] + ts2[i]);
    hsup[i] = (1.f-z)*mself[i] + z*mtm[i];
}

__global__ void copy_out_kernel(const float* __restrict__ vf, const float* __restrict__ master,
                                float* __restrict__ out)
{
    int i = blockIdx.x*256 + threadIdx.x;
    const int nvf4 = SLAB/4;
    if (i < nvf4) ((float4*)out)[i] = ((const float4*)vf)[i];
    else ((float4*)out)[i] = ((const float4*)master)[i - nvf4];
}

// ---------------------------------------------------------------------------
extern "C" void kernel_launch(void* const* d_in, const int* in_sizes, int n_in,
                              void* d_out, int out_size, void* d_ws, size_t ws_size,
                              hipStream_t stream)
{
    (void)in_sizes; (void)n_in; (void)out_size; (void)ws_size;
    const float* vmask = (const float*)d_in[1];
    const int*   vertex= (const int*)d_in[2];
    const int*   edge  = (const int*)d_in[3];
    const int*   aadj  = (const int*)d_in[4];
    const int*   badj  = (const int*)d_in[5];
    const float* nbm   = (const float*)d_in[6];
    const float* atomf = (const float*)d_in[7];
    const float* bondf = (const float*)d_in[8];
    const float* emb_w = (const float*)d_in[9];
    const float* emb_b = (const float*)d_in[10];
    const float* u1_w  = (const float*)d_in[11];
    const float* u1_b  = (const float*)d_in[12];
    const float* u2_w  = (const float*)d_in[13];
    const float* u2_b  = (const float*)d_in[14];
    const float* fu_w  = (const float*)d_in[15];
    const float* fu_b  = (const float*)d_in[16];
    const float* wvm_w = (const float*)d_in[17];
    const float* wvm_b = (const float*)d_in[18];
    const float* wmain_w=(const float*)d_in[19];
    const float* wmain_b=(const float*)d_in[20];
    const float* wbmm_w= (const float*)d_in[21];
    const float* wbmm_b= (const float*)d_in[22];
    const float* khead_w=(const float*)d_in[23];
    const float* khead_b=(const float*)d_in[24];
    const float* wmaster_w=(const float*)d_in[25];
    const float* wmaster_b=(const float*)d_in[26];
    const float* wm2m_w= (const float*)d_in[27];
    const float* wm2m_b= (const float*)d_in[28];
    const float* wzm1_w= (const float*)d_in[29];
    const float* wzm1_b= (const float*)d_in[30];
    const float* wzm2_w= (const float*)d_in[31];
    const float* wzm2_b= (const float*)d_in[32];
    const float* wzs1_w= (const float*)d_in[33];
    const float* wzs1_b= (const float*)d_in[34];
    const float* wzs2_w= (const float*)d_in[35];
    const float* wzs2_b= (const float*)d_in[36];
    const float* g_wih = (const float*)d_in[37];
    const float* g_whh = (const float*)d_in[38];
    const float* g_bih = (const float*)d_in[39];
    const float* g_bhh = (const float*)d_in[40];
    const float* gm_wih= (const float*)d_in[41];
    const float* gm_whh= (const float*)d_in[42];
    const float* gm_bih= (const float*)d_in[43];
    const float* gm_bhh= (const float*)d_in[44];

    float* ws     = (float*)d_ws;
    float* vf     = ws;
    float* h0     = vf + SLAB;
    float* S      = h0 + SLAB;            // 4 slabs
    float* e_init = S + 4*(size_t)SLAB;
    float* att    = e_init + BB*EE*BF;
    float* kmm    = att + BB*KK*NN;
    float* master = kmm + BB*KK*HH;
    float* m2m    = master + BB*HH;
    float* mself  = m2m + BB*HH;
    float* t2     = mself + BB*HH;
    float* mtm    = t2 + BB*HH;
    float* ts1    = mtm + BB*HH;
    float* ts2    = ts1 + BB*HH;
    float* hsup   = ts2 + BB*HH;
    float* WTih_s = hsup + BB*HH;
    float* WThh_s = WTih_s + 128*384;
    // bf16 hi/lo weight tables (as short); each table is 2*total shorts
    short* wt_emb   = (short*)(WThh_s + 128*384);
    short* wt_wvm   = wt_emb   + 2*12288;
    short* wt_wmain = wt_wvm   + 2*196608;
    short* wt_u1    = wt_wmain + 2*196608;
    short* wt_u2    = wt_u1    + 2*61440;
    short* wt_fu    = wt_u2    + 2*98304;
    short* wt_wzm1  = wt_fu    + 2*49152;
    short* wt_gih   = wt_wzm1  + 2*49152;
    short* wt_ghh   = wt_gih   + 2*49152;

    const float* NPF = nullptr;
    const int*   NPI = nullptr;
    float*       NPW = nullptr;

    // master-GRU fp32 transposes
    transpose384_kernel<<<192, 256, 0, stream>>>(gm_wih, WTih_s);
    transpose384_kernel<<<192, 256, 0, stream>>>(gm_whh, WThh_s);

    // bf16 hi/lo weight conversions
    wcvt_t<<<(12288+255)/256,     256, 0, stream>>>(emb_w,   wt_emb,   82, 96, 12288);
    wcvt_t<<<(196608+255)/256,    256, 0, stream>>>(wvm_w,   wt_wvm,  128,128, 196608);
    wcvt_t<<<(196608+255)/256,    256, 0, stream>>>(wmain_w, wt_wmain,128,128, 196608);
    wcvt_t<<<(61440+255)/256,     256, 0, stream>>>(u1_w,    wt_u1,   134,160, 61440);
    wcvt_t<<<(98304+255)/256,     256, 0, stream>>>(u2_w,    wt_u2,   256,256, 98304);
    wcvt_t<<<(49152+255)/256,     256, 0, stream>>>(fu_w,    wt_fu,   128,128, 49152);
    wcvt_t<<<(49152+255)/256,     256, 0, stream>>>(wzm1_w,  wt_wzm1, 128,128, 49152);
    wcvt_d<<<(49152+255)/256,     256, 0, stream>>>(g_wih,   wt_gih,  49152);
    wcvt_d<<<(49152+255)/256,     256, 0, stream>>>(g_whh,   wt_ghh,  49152);

    e_gather_kernel<<<(BB*EE*BF + 255)/256, 256, 0, stream>>>(bondf, edge, e_init);

    // embed: vf = gelu((atomf[vertex]*vm) @ emb_w + b), dual store h0
    mgemm<1,1><<<dim3(256,1,1), 256, 0, stream>>>(
        atomf, NPF, wt_emb, emb_b, vf, h0, AF, 96,
        vertex, NPI, vmask, NPF, NPF, NPF, NPF, 0.f, 0.f, 1, 0ULL, 0ULL, 12288ULL);

    master_init_kernel<<<BB, 256, 0, stream>>>(vf, vmask, master);

    for (int i = 0; i < LL; ++i) {
        float theta = logf(0.5f/(float)(i+1) + 1.f);

        // mv = tanh(vf @ wvm[i,k] + b) -> S[k]
        mgemm<0,2><<<dim3(256,1,4), 256, 0, stream>>>(
            vf, NPF, wt_wvm + (size_t)i*4*16384, wvm_b + (size_t)i*4*128, S, NPW, 128, 128,
            NPI, NPI, NPF, NPF, NPF, NPF, NPF, 0.f, 0.f, 1,
            (unsigned long long)SLAB, 16384ULL, 196608ULL);
        score_kernel<<<BB*KK*NN/4, 256, 0, stream>>>(S, master, wbmm_w + i*KK*HH, wbmm_b + i*KK, att);
        softmax_kernel<<<BB*KK, 256, 0, stream>>>(att, vmask);
        // proj = vf @ wmain[i,k] + b -> S[k]
        mgemm<0,0><<<dim3(256,1,4), 256, 0, stream>>>(
            vf, NPF, wt_wmain + (size_t)i*4*16384, wmain_b + (size_t)i*4*128, S, NPW, 128, 128,
            NPI, NPI, NPF, NPF, NPF, NPF, NPF, 0.f, 0.f, 1,
            (unsigned long long)SLAB, 16384ULL, 196608ULL);
        kmm_kernel<<<BB*KK, 128, 0, stream>>>(S, att, kmm);
        // main_to_master = tanh(kmm @ khead + b), M=64 K=512 (fp32 path)
        gemm_kernel<0,2><<<dim3(1,1,1), 256, 0, stream>>>(
            kmm, NPF, khead_w + (size_t)i*KK*HH*HH, khead_b + i*HH, mtm, NPW, BB, KK*HH,
            NPI, NPI, NPF, NPF, NPF, NPF, NPF, 0.f, 0.f, 1, 0ULL);
        // u1 -> nl in S0
        mgemm<3,5><<<dim3(2048,1,1), 256, 0, stream>>>(
            vf, e_init, wt_u1 + (size_t)i*128*160, u1_b + i*HH, S, NPW, 134, 160,
            aadj, badj, NPF, nbm, NPF, NPF, NPF, 0.f, 0.f, 1, 0ULL, 0ULL, 61440ULL);
        // u2: hi = concat(nl, vf) @ u2 + b -> S1
        mgemm<2,0><<<dim3(256,1,1), 256, 0, stream>>>(
            S, vf, wt_u2 + (size_t)i*128*256, u2_b + i*HH, S + SLAB, NPW, 256, 256,
            NPI, NPI, NPF, NPF, NPF, NPF, NPF, 0.f, 0.f, 1, 0ULL, 0ULL, 98304ULL);
        pw_support_kernel<<<4096, 256, 0, stream>>>(S + SLAB, h0);
        // self_vertex -> S2
        mgemm<0,3><<<dim3(256,1,1), 256, 0, stream>>>(
            S + SLAB, NPF, wt_fu + (size_t)i*16384, fu_b + i*HH, S + 2*(size_t)SLAB, NPW, 128, 128,
            NPI, NPI, NPF, NPF, S + SLAB, NPF, NPF, theta, 1.f - theta, 1, 0ULL, 0ULL, 49152ULL);
        // master small mats (fp32)
        gemm_kernel<0,1><<<dim3(1,1,1), 256, 0, stream>>>(
            master, NPF, wm2m_w + (size_t)i*HH*HH, wm2m_b + i*HH, m2m, NPW, BB, HH,
            NPI, NPI, NPF, NPF, NPF, NPF, NPF, 0.f, 0.f, 1, 0ULL);
        gemm_kernel<0,1><<<dim3(1,1,1), 256, 0, stream>>>(
            master, NPF, wmaster_w + (size_t)i*HH*HH, wmaster_b + i*HH, mself, NPW, BB, HH,
            NPI, NPI, NPF, NPF, NPF, NPF, NPF, 0.f, 0.f, 1, 0ULL);
        gemm_kernel<0,0><<<dim3(1,1,1), 256, 0, stream>>>(
            m2m, NPF, wzm2_w + (size_t)i*HH*HH, wzm2_b + i*HH, t2, NPW, BB, HH,
            NPI, NPI, NPF, NPF, NPF, NPF, NPF, 0.f, 0.f, 1, 0ULL);
        // hidden_main -> S3
        mgemm<0,4><<<dim3(256,1,1), 256, 0, stream>>>(
            S + 2*(size_t)SLAB, NPF, wt_wzm1 + (size_t)i*16384, wzm1_b + i*HH, S + 3*(size_t)SLAB, NPW, 128, 128,
            NPI, NPI, NPF, NPF, S + 2*(size_t)SLAB, t2, m2m, 0.f, 0.f, NN, 0ULL, 0ULL, 49152ULL);
        // gi = hidden_main @ wih^T + bih, 3 gate slabs -> S0..S2
        mgemm<0,0><<<dim3(256,1,3), 256, 0, stream>>>(
            S + 3*(size_t)SLAB, NPF, wt_gih, g_bih, S, NPW, 128, 128,
            NPI, NPI, NPF, NPF, NPF, NPF, NPF, 0.f, 0.f, 1,
            (unsigned long long)SLAB, 16384ULL, 49152ULL);
        // vf = GRU(hidden_main, vf) fused gh-MFMA + combine
        gru_mfma<<<dim3(512,1,1), 256, 0, stream>>>(S, vf, wt_ghh, g_bhh, 49152ULL);
        // master path tail (fp32)
        gemm_kernel<0,0><<<dim3(1,1,1), 256, 0, stream>>>(
            mself, NPF, wzs1_w + (size_t)i*HH*HH, wzs1_b + i*HH, ts1, NPW, BB, HH,
            NPI, NPI, NPF, NPF, NPF, NPF, NPF, 0.f, 0.f, 1, 0ULL);
        gemm_kernel<0,0><<<dim3(1,1,1), 256, 0, stream>>>(
            mtm, NPF, wzs2_w + (size_t)i*HH*HH, wzs2_b + i*HH, ts2, NPW, BB, HH,
            NPI, NPI, NPF, NPF, NPF, NPF, NPF, 0.f, 0.f, 1, 0ULL);
        pw_hsup_kernel<<<(BB*HH + 255)/256, 256, 0, stream>>>(ts1, ts2, mself, mtm, hsup);
        gru_kernel<<<BB/32, 256, 0, stream>>>(hsup, master, master, WTih_s, WThh_s, gm_bih, gm_bhh);
    }

    copy_out_kernel<<<(SLAB + BB*HH)/4/256, 256, 0, stream>>>(vf, master, (float*)d_out);
}

// Round 4
// 1628.086 us; speedup vs baseline: 2.6593x; 2.0816x over previous
//
#include <hip/hip_runtime.h>
#include <hip/hip_bf16.h>
#include <cmath>

// Problem constants
#define BB 64
#define NN 512
#define NBS 8
#define EE 2048
#define HH 128
#define LL 3
#define KK 4
#define AF 82
#define BF 6
#define SLAB 4194304   // B*N*H floats

typedef __attribute__((ext_vector_type(8))) short bf16x8;
typedef __attribute__((ext_vector_type(4))) float f32x4;

__device__ __forceinline__ float gelu1(float x){ return 0.5f*x*(1.f+erff(x*0.7071067811865475f)); }
__device__ __forceinline__ float sig1(float x){ return 1.f/(1.f+expf(-x)); }
__device__ __forceinline__ short f2bs(float x){ __hip_bfloat16 b=__float2bfloat16(x); return *reinterpret_cast<short*>(&b); }
__device__ __forceinline__ float bs2f(short s){ unsigned u = ((unsigned)(unsigned short)s) << 16; union{unsigned u; float f;} c; c.u=u; return c.f; }
__device__ __forceinline__ void split2(float v, short& hi, short& lo){ hi = f2bs(v); lo = f2bs(v - bs2f(hi)); }

// ---------------------------------------------------------------------------
// Split-bf16 (emulated fp32) MFMA GEMM: C[M,128] = epi(A[M,K] @ W[K,128] + b)
// Weight tables: hi at WT[col*Kpad+k], lo at WT[loOff + col*Kpad+k].
// acc += a_hi*w_hi + a_lo*w_hi + a_hi*w_lo  (rel err ~2^-17)
// AMODE: 0 contiguous fp32 A; 1 atom-gather*vmask; 2 concat(A,A2); 3 u1 gather
// EMODE: 0 bias; 1 gelu(+C2); 2 tanh; 3 theta-blend; 4 z-gate; 5 u1 segsum
// ---------------------------------------------------------------------------
template<int AMODE, int EMODE>
__global__ __launch_bounds__(256) void mgemm(
    const float* __restrict__ A, const float* __restrict__ A2,
    const short* __restrict__ WT, const float* __restrict__ bias,
    float* __restrict__ C, float* __restrict__ C2,
    int K, int Kpad,
    const int* __restrict__ g1, const int* __restrict__ g2,
    const float* __restrict__ vmask, const float* __restrict__ nbm,
    const float* __restrict__ extraM, const float* __restrict__ extraB,
    const float* __restrict__ extraB2,
    float p0, float p1, int rowsPerB,
    unsigned long long zCs, unsigned long long zWs, unsigned long long loOff)
{
    const int t = threadIdx.x;
    const int lane = t & 63, wv = t >> 6;
    const int quad = lane >> 4, ml = lane & 15;
    const int z = blockIdx.z;
    const short* WTz = WT + (size_t)z * zWs;
    const float* bz  = bias + (size_t)z * 128;
    float* Cz        = C + (size_t)z * zCs;
    const int m0 = blockIdx.x * 128 + wv * 32;

    const int r0 = m0 + ml, r1 = m0 + 16 + ml;
    int ga0 = 0, ga1 = 0, gb0 = 0, gb1 = 0; float vm0 = 0.f, vm1 = 0.f;
    if (AMODE == 1) { ga0 = g1[r0]; ga1 = g1[r1]; vm0 = vmask[r0]; vm1 = vmask[r1]; }
    if (AMODE == 3) { ga0 = g1[r0]; ga1 = g1[r1]; gb0 = g2[r0]; gb1 = g2[r1]; }

    f32x4 acc[16];
    #pragma unroll
    for (int i = 0; i < 16; ++i) acc[i] = (f32x4){0.f,0.f,0.f,0.f};

    const int nchunk = Kpad >> 5;
    const short* wcol = WTz + (size_t)ml * Kpad;

    for (int kc = 0; kc < nchunk; ++kc) {
        const int kq = kc*32 + quad*8;
        float av0[8], av1[8];
        if (AMODE == 0) {
            const float* p0r = A + (size_t)r0*K + kq;
            const float* p1r = A + (size_t)r1*K + kq;
            float4 a0 = *(const float4*)p0r, a1 = *(const float4*)(p0r+4);
            float4 b0 = *(const float4*)p1r, b1 = *(const float4*)(p1r+4);
            av0[0]=a0.x; av0[1]=a0.y; av0[2]=a0.z; av0[3]=a0.w;
            av0[4]=a1.x; av0[5]=a1.y; av0[6]=a1.z; av0[7]=a1.w;
            av1[0]=b0.x; av1[1]=b0.y; av1[2]=b0.z; av1[3]=b0.w;
            av1[4]=b1.x; av1[5]=b1.y; av1[6]=b1.z; av1[7]=b1.w;
        } else if (AMODE == 1) {
            const float* p0r = A + (size_t)ga0*K + kq;
            const float* p1r = A + (size_t)ga1*K + kq;
            #pragma unroll
            for (int j2 = 0; j2 < 4; ++j2) {
                int k = kq + 2*j2;
                if (k + 2 <= K) {
                    float2 v0 = *(const float2*)(p0r + 2*j2);
                    float2 v1 = *(const float2*)(p1r + 2*j2);
                    av0[2*j2]=v0.x*vm0; av0[2*j2+1]=v0.y*vm0;
                    av1[2*j2]=v1.x*vm1; av1[2*j2+1]=v1.y*vm1;
                } else { av0[2*j2]=0.f; av0[2*j2+1]=0.f; av1[2*j2]=0.f; av1[2*j2+1]=0.f; }
            }
        } else if (AMODE == 2) {
            const float* p0r = (kq < 128) ? A + (size_t)r0*128 + kq : A2 + (size_t)r0*128 + (kq-128);
            const float* p1r = (kq < 128) ? A + (size_t)r1*128 + kq : A2 + (size_t)r1*128 + (kq-128);
            float4 a0 = *(const float4*)p0r, a1 = *(const float4*)(p0r+4);
            float4 b0 = *(const float4*)p1r, b1 = *(const float4*)(p1r+4);
            av0[0]=a0.x; av0[1]=a0.y; av0[2]=a0.z; av0[3]=a0.w;
            av0[4]=a1.x; av0[5]=a1.y; av0[6]=a1.z; av0[7]=a1.w;
            av1[0]=b0.x; av1[1]=b0.y; av1[2]=b0.z; av1[3]=b0.w;
            av1[4]=b1.x; av1[5]=b1.y; av1[6]=b1.z; av1[7]=b1.w;
        } else { // AMODE 3
            if (kq < 128) {
                const float* p0r = A + (size_t)ga0*128 + kq;
                const float* p1r = A + (size_t)ga1*128 + kq;
                float4 a0 = *(const float4*)p0r, a1 = *(const float4*)(p0r+4);
                float4 b0 = *(const float4*)p1r, b1 = *(const float4*)(p1r+4);
                av0[0]=a0.x; av0[1]=a0.y; av0[2]=a0.z; av0[3]=a0.w;
                av0[4]=a1.x; av0[5]=a1.y; av0[6]=a1.z; av0[7]=a1.w;
                av1[0]=b0.x; av1[1]=b0.y; av1[2]=b0.z; av1[3]=b0.w;
                av1[4]=b1.x; av1[5]=b1.y; av1[6]=b1.z; av1[7]=b1.w;
            } else if (kq == 128) {
                const float* p0r = A2 + (size_t)gb0*6;
                const float* p1r = A2 + (size_t)gb1*6;
                float2 x0=*(const float2*)p0r, x1=*(const float2*)(p0r+2), x2=*(const float2*)(p0r+4);
                float2 y0=*(const float2*)p1r, y1=*(const float2*)(p1r+2), y2=*(const float2*)(p1r+4);
                av0[0]=x0.x; av0[1]=x0.y; av0[2]=x1.x; av0[3]=x1.y; av0[4]=x2.x; av0[5]=x2.y; av0[6]=0.f; av0[7]=0.f;
                av1[0]=y0.x; av1[1]=y0.y; av1[2]=y1.x; av1[3]=y1.y; av1[4]=y2.x; av1[5]=y2.y; av1[6]=0.f; av1[7]=0.f;
            } else {
                #pragma unroll
                for (int j = 0; j < 8; ++j) { av0[j]=0.f; av1[j]=0.f; }
            }
        }
        bf16x8 a0h, a0l, a1h, a1l;
        #pragma unroll
        for (int j = 0; j < 8; ++j) {
            short h, l;
            split2(av0[j], h, l); a0h[j]=h; a0l[j]=l;
            split2(av1[j], h, l); a1h[j]=h; a1l[j]=l;
        }

        #pragma unroll
        for (int nt = 0; nt < 8; ++nt) {
            const short* bp = wcol + (size_t)nt*16*Kpad + kq;
            bf16x8 bh = *(const bf16x8*)bp;
            bf16x8 bl = *(const bf16x8*)(bp + loOff);
            acc[nt] = __builtin_amdgcn_mfma_f32_16x16x32_bf16(a0h, bh, acc[nt], 0,0,0);
            acc[nt] = __builtin_amdgcn_mfma_f32_16x16x32_bf16(a0l, bh, acc[nt], 0,0,0);
            acc[nt] = __builtin_amdgcn_mfma_f32_16x16x32_bf16(a0h, bl, acc[nt], 0,0,0);
            acc[8+nt] = __builtin_amdgcn_mfma_f32_16x16x32_bf16(a1h, bh, acc[8+nt], 0,0,0);
            acc[8+nt] = __builtin_amdgcn_mfma_f32_16x16x32_bf16(a1l, bh, acc[8+nt], 0,0,0);
            acc[8+nt] = __builtin_amdgcn_mfma_f32_16x16x32_bf16(a1h, bl, acc[8+nt], 0,0,0);
        }
    }

    // --- epilogue ---
    if constexpr (EMODE == 5) {
        __shared__ float red[4][16][132];
        #pragma unroll
        for (int mt = 0; mt < 2; ++mt) {
            __syncthreads();
            #pragma unroll
            for (int nt = 0; nt < 8; ++nt) {
                int col = nt*16 + ml;
                float bj = bz[col];
                #pragma unroll
                for (int r = 0; r < 4; ++r) {
                    int gm = m0 + mt*16 + quad*4 + r;
                    red[wv][quad*4+r][col] = gelu1(acc[mt*8+nt][r] + bj) * nbm[gm];
                }
            }
            __syncthreads();
            #pragma unroll
            for (int q = 0; q < 4; ++q) {
                int idx = lane*4 + q;
                int seg = idx >> 7, col = idx & 127;
                float s = 0.f;
                #pragma unroll
                for (int ss = 0; ss < 8; ++ss) s += red[wv][seg*8+ss][col];
                Cz[(size_t)(m0/8 + mt*2 + seg)*128 + col] = s;
            }
        }
        return;
    }

    #pragma unroll
    for (int mt = 0; mt < 2; ++mt) {
        #pragma unroll
        for (int nt = 0; nt < 8; ++nt) {
            int col = nt*16 + ml;
            float bj = bz[col];
            #pragma unroll
            for (int r = 0; r < 4; ++r) {
                int gm = m0 + mt*16 + quad*4 + r;
                float v = acc[mt*8+nt][r] + bj;
                if (EMODE == 1) v = gelu1(v);
                else if (EMODE == 2) v = tanhf(v);
                else if (EMODE == 3) v = p0*v + p1*extraM[(size_t)gm*128 + col];
                else if (EMODE == 4) {
                    int bi = gm / rowsPerB;
                    float zg = sig1(v + extraB[(size_t)bi*128 + col]);
                    v = (1.f-zg)*extraM[(size_t)gm*128 + col] + zg*extraB2[(size_t)bi*128 + col];
                }
                Cz[(size_t)gm*128 + col] = v;
                if (EMODE == 1 && C2 != nullptr) C2[(size_t)gm*128 + col] = v;
            }
        }
    }
}

// ---------------------------------------------------------------------------
// Fused GRU (main): gh = h @ whh^T via split-bf16 MFMA, combine with gi slabs,
// write vf in place. Each wave: 16 rows x 384 cols.
// ---------------------------------------------------------------------------
__global__ __launch_bounds__(256) void gru_mfma(
    const float* __restrict__ gi,   // 3 slabs of SLAB: r,z,n
    float* __restrict__ vf,
    const short* __restrict__ whh,  // [384][128] bf16, lo at +loOff
    const float* __restrict__ bhh,
    unsigned long long loOff)
{
    const int t = threadIdx.x;
    const int lane = t & 63, wv = t >> 6;
    const int quad = lane >> 4, ml = lane & 15;
    const int m0 = blockIdx.x * 64 + wv * 16;
    const int arow = m0 + ml;

    f32x4 acc[24];
    #pragma unroll
    for (int i = 0; i < 24; ++i) acc[i] = (f32x4){0.f,0.f,0.f,0.f};

    for (int kc = 0; kc < 4; ++kc) {
        const int kq = kc*32 + quad*8;
        const float* p = vf + (size_t)arow*128 + kq;
        float4 v0 = *(const float4*)p, v1 = *(const float4*)(p+4);
        float av[8] = {v0.x,v0.y,v0.z,v0.w,v1.x,v1.y,v1.z,v1.w};
        bf16x8 ah, al;
        #pragma unroll
        for (int j = 0; j < 8; ++j) { short h,l; split2(av[j],h,l); ah[j]=h; al[j]=l; }
        #pragma unroll
        for (int g = 0; g < 3; ++g) {
            #pragma unroll
            for (int nt = 0; nt < 8; ++nt) {
                const short* bp = whh + (size_t)(g*128 + nt*16 + ml)*128 + kq;
                bf16x8 bh = *(const bf16x8*)bp;
                bf16x8 bl = *(const bf16x8*)(bp + loOff);
                acc[g*8+nt] = __builtin_amdgcn_mfma_f32_16x16x32_bf16(ah, bh, acc[g*8+nt], 0,0,0);
                acc[g*8+nt] = __builtin_amdgcn_mfma_f32_16x16x32_bf16(al, bh, acc[g*8+nt], 0,0,0);
                acc[g*8+nt] = __builtin_amdgcn_mfma_f32_16x16x32_bf16(ah, bl, acc[g*8+nt], 0,0,0);
            }
        }
    }

    #pragma unroll
    for (int nt = 0; nt < 8; ++nt) {
        int col = nt*16 + ml;
        float br = bhh[col], bz2 = bhh[128+col], bn = bhh[256+col];
        #pragma unroll
        for (int r = 0; r < 4; ++r) {
            int gm = m0 + quad*4 + r;
            size_t off = (size_t)gm*128 + col;
            float gr = sig1(gi[off] + acc[nt][r] + br);
            float gz = sig1(gi[(size_t)SLAB + off] + acc[8+nt][r] + bz2);
            float gn = tanhf(gi[2ull*SLAB + off] + gr*(acc[16+nt][r] + bn));
            float hv = vf[off];
            vf[off] = (1.f-gz)*gn + gz*hv;
        }
    }
}

// ---------------------------------------------------------------------------
// Fused master path: per-layer, grid=64 blocks (one per batch row), 256 thr.
// Does mtm, m2m, mself, t2, z_master, hidden_super, and the master GRU.
// Stores m2m/t2 (needed by the big-path z-gate) and updates master in place.
// Weights are shared across blocks -> L2-resident.
// ---------------------------------------------------------------------------
__global__ __launch_bounds__(256) void master_fused(
    const float* __restrict__ kmm,        // [B][512]
    float* __restrict__ master,           // [B][128] in/out
    const float* __restrict__ khead_w, const float* __restrict__ khead_b,
    const float* __restrict__ wm2m_w,  const float* __restrict__ wm2m_b,
    const float* __restrict__ wmaster_w, const float* __restrict__ wmaster_b,
    const float* __restrict__ wzm2_w,  const float* __restrict__ wzm2_b,
    const float* __restrict__ wzs1_w,  const float* __restrict__ wzs1_b,
    const float* __restrict__ wzs2_w,  const float* __restrict__ wzs2_b,
    const float* __restrict__ WTih, const float* __restrict__ WThh,  // [128][384]
    const float* __restrict__ bih, const float* __restrict__ bhh,
    float* __restrict__ m2m_out, float* __restrict__ t2_out)
{
    __shared__ float xs[512], ms[128];
    __shared__ float v_mtm[128], v_m2m[128], v_mself[128], v_t2[128];
    __shared__ float v_ts1[128], v_ts2[128], v_hsup[128];
    __shared__ float gi[384], gh[384];
    __shared__ float red[256];
    const int t = threadIdx.x;
    const int b = blockIdx.x;

    // load kmm row (512) and master row (128)
    xs[t] = kmm[(size_t)b*512 + t];
    xs[256 + t] = kmm[(size_t)b*512 + 256 + t];
    if (t < 128) ms[t] = master[(size_t)b*128 + t];
    __syncthreads();

    const int c = t & 127, p = t >> 7;

    // helper macro: matvec K into out with activation
    auto matvec = [&](const float* src, const float* __restrict__ W,
                      const float* __restrict__ bias, int K, float* out, int act) {
        int half = K >> 1;
        int k0 = p*half, k1 = k0 + half;
        float s = 0.f;
        for (int k = k0; k < k1; ++k) s += src[k]*W[(size_t)k*128 + c];
        red[t] = s; __syncthreads();
        if (t < 128) {
            float v = red[c] + red[c+128] + bias[c];
            if (act == 1) v = gelu1(v); else if (act == 2) v = tanhf(v);
            out[c] = v;
        }
        __syncthreads();
    };

    matvec(xs, khead_w, khead_b, 512, v_mtm, 2);     // main_to_master
    matvec(ms, wm2m_w, wm2m_b, 128, v_m2m, 1);       // m2m
    matvec(ms, wmaster_w, wmaster_b, 128, v_mself, 1); // mself
    matvec(v_m2m, wzm2_w, wzm2_b, 128, v_t2, 0);     // t2
    matvec(v_mself, wzs1_w, wzs1_b, 128, v_ts1, 0);
    matvec(v_mtm, wzs2_w, wzs2_b, 128, v_ts2, 0);

    if (t < 128) {
        float z = sig1(v_ts1[t] + v_ts2[t]);
        v_hsup[t] = (1.f-z)*v_mself[t] + z*v_mtm[t];
        m2m_out[(size_t)b*128 + t] = v_m2m[t];
        t2_out[(size_t)b*128 + t]  = v_t2[t];
    }
    __syncthreads();

    // master GRU: gi = hsup @ wih^T + bih; gh = master @ whh^T + bhh
    for (int j = t; j < 384; j += 256) {
        float a = 0.f, h2 = 0.f;
        for (int k = 0; k < 128; ++k) {
            a  += v_hsup[k]*WTih[(size_t)k*384 + j];
            h2 += ms[k]*WThh[(size_t)k*384 + j];
        }
        gi[j] = a + bih[j];
        gh[j] = h2 + bhh[j];
    }
    __syncthreads();
    if (t < 128) {
        float r = sig1(gi[t] + gh[t]);
        float z = sig1(gi[128+t] + gh[128+t]);
        float n = tanhf(gi[256+t] + r*gh[256+t]);
        master[(size_t)b*128 + t] = (1.f-z)*n + z*ms[t];
    }
}

// ---------------------------------------------------------------------------
// Weight conversion: dst[i]=hi, dst[total+i]=lo
__global__ void wcvt_t(const float* __restrict__ src, short* __restrict__ dst,
                       int K, int Kpad, int total)
{
    int i = blockIdx.x*256 + threadIdx.x;
    if (i >= total) return;
    int z = i / (128*Kpad); int rem = i - z*128*Kpad;
    int col = rem / Kpad; int k = rem - col*Kpad;
    float v = (k < K) ? src[(size_t)z*K*128 + (size_t)k*128 + col] : 0.f;
    short h, l; split2(v, h, l);
    dst[i] = h; dst[total + i] = l;
}

__global__ void wcvt_d(const float* __restrict__ src, short* __restrict__ dst, int n)
{
    int i = blockIdx.x*256 + threadIdx.x;
    if (i < n) { short h,l; split2(src[i], h, l); dst[i]=h; dst[n+i]=l; }
}

// ---------------------------------------------------------------------------
// small helper kernels
// ---------------------------------------------------------------------------
__global__ void transpose384_kernel(const float* __restrict__ src, float* __restrict__ dst)
{
    int o = blockIdx.x*256 + threadIdx.x;
    if (o >= 49152) return;
    int k = o / 384, j = o - k*384;
    dst[o] = src[j*128 + k];
}

__global__ void e_gather_kernel(const float* __restrict__ bondf, const int* __restrict__ edge,
                                float* __restrict__ e_init)
{
    int idx = blockIdx.x*256 + threadIdx.x;
    if (idx >= BB*EE*BF) return;
    int m = idx / BF, j = idx - m*BF;
    e_init[idx] = bondf[edge[m]*BF + j];
}

__global__ __launch_bounds__(256) void master_init_kernel(const float* __restrict__ vf,
                                                          const float* __restrict__ vm,
                                                          float* __restrict__ master)
{
    __shared__ float red[256];
    int b = blockIdx.x; int t = threadIdx.x; int hcol = t & 127; int half = t >> 7;
    float s = 0.f;
    for (int n = half; n < NN; n += 2)
        s += vf[((size_t)b*NN + n)*HH + hcol] * vm[b*NN + n];
    red[t] = s; __syncthreads();
    if (half == 0) master[b*HH + hcol] = red[hcol] + red[hcol + 128];
}

__global__ __launch_bounds__(256) void score_kernel(const float* __restrict__ S,
                                                    const float* __restrict__ master,
                                                    const float* __restrict__ wbw,
                                                    const float* __restrict__ wbb,
                                                    float* __restrict__ score)
{
    int w = threadIdx.x >> 6; int lane = threadIdx.x & 63;
    int row = blockIdx.x*4 + w;
    int b = row >> 11;
    int k = (row >> 9) & 3;
    int n = row & 511;
    const float* srow = S + (size_t)k*SLAB + ((size_t)b*NN + n)*HH;
    const float* mrow = master + b*HH;
    const float* wk   = wbw + k*HH;
    float p = srow[lane]*mrow[lane]*wk[lane] + srow[lane+64]*mrow[lane+64]*wk[lane+64];
    #pragma unroll
    for (int off = 32; off; off >>= 1) p += __shfl_down(p, off);
    if (lane == 0) score[row] = p + wbb[k];
}

__global__ __launch_bounds__(256) void softmax_kernel(float* __restrict__ att,
                                                      const float* __restrict__ vm)
{
    __shared__ float red[256];
    int t = threadIdx.x;
    int bk = blockIdx.x; int b = bk >> 2;
    float* a = att + (size_t)bk*NN;
    float v0 = a[t], v1 = a[t+256];
    red[t] = fmaxf(v0, v1); __syncthreads();
    for (int s = 128; s; s >>= 1) { if (t < s) red[t] = fmaxf(red[t], red[t+s]); __syncthreads(); }
    float mx = red[0]; __syncthreads();
    float e0 = expf(v0 - mx) * vm[b*NN + t];
    float e1 = expf(v1 - mx) * vm[b*NN + t + 256];
    red[t] = e0 + e1; __syncthreads();
    for (int s = 128; s; s >>= 1) { if (t < s) red[t] += red[t+s]; __syncthreads(); }
    float inv = 1.f / (red[0] + 1e-6f);
    a[t] = e0*inv; a[t+256] = e1*inv;
}

__global__ __launch_bounds__(128) void kmm_kernel(const float* __restrict__ S,
                                                  const float* __restrict__ att,
                                                  float* __restrict__ kmm)
{
    int b = blockIdx.x >> 2, k = blockIdx.x & 3;
    int d = threadIdx.x;
    const float* at = att + ((size_t)b*KK + k)*NN;
    const float* Sk = S + (size_t)k*SLAB + (size_t)b*NN*HH;
    float acc = 0.f;
    for (int n = 0; n < NN; ++n) acc += at[n] * Sk[(size_t)n*HH + d];
    kmm[((size_t)b*KK + k)*HH + d] = acc;
}

__global__ void pw_support_kernel(float* __restrict__ hi, const float* __restrict__ h0)
{
    int i = blockIdx.x*256 + threadIdx.x;
    float4 a = ((const float4*)hi)[i];
    float4 b = ((const float4*)h0)[i];
    a.x = 0.9f*a.x + 0.1f*b.x; a.y = 0.9f*a.y + 0.1f*b.y;
    a.z = 0.9f*a.z + 0.1f*b.z; a.w = 0.9f*a.w + 0.1f*b.w;
    ((float4*)hi)[i] = a;
}

__global__ void copy_out_kernel(const float* __restrict__ vf, const float* __restrict__ master,
                                float* __restrict__ out)
{
    int i = blockIdx.x*256 + threadIdx.x;
    const int nvf4 = SLAB/4;
    if (i < nvf4) ((float4*)out)[i] = ((const float4*)vf)[i];
    else ((float4*)out)[i] = ((const float4*)master)[i - nvf4];
}

// ---------------------------------------------------------------------------
extern "C" void kernel_launch(void* const* d_in, const int* in_sizes, int n_in,
                              void* d_out, int out_size, void* d_ws, size_t ws_size,
                              hipStream_t stream)
{
    (void)in_sizes; (void)n_in; (void)out_size; (void)ws_size;
    const float* vmask = (const float*)d_in[1];
    const int*   vertex= (const int*)d_in[2];
    const int*   edge  = (const int*)d_in[3];
    const int*   aadj  = (const int*)d_in[4];
    const int*   badj  = (const int*)d_in[5];
    const float* nbm   = (const float*)d_in[6];
    const float* atomf = (const float*)d_in[7];
    const float* bondf = (const float*)d_in[8];
    const float* emb_w = (const float*)d_in[9];
    const float* emb_b = (const float*)d_in[10];
    const float* u1_w  = (const float*)d_in[11];
    const float* u1_b  = (const float*)d_in[12];
    const float* u2_w  = (const float*)d_in[13];
    const float* u2_b  = (const float*)d_in[14];
    const float* fu_w  = (const float*)d_in[15];
    const float* fu_b  = (const float*)d_in[16];
    const float* wvm_w = (const float*)d_in[17];
    const float* wvm_b = (const float*)d_in[18];
    const float* wmain_w=(const float*)d_in[19];
    const float* wmain_b=(const float*)d_in[20];
    const float* wbmm_w= (const float*)d_in[21];
    const float* wbmm_b= (const float*)d_in[22];
    const float* khead_w=(const float*)d_in[23];
    const float* khead_b=(const float*)d_in[24];
    const float* wmaster_w=(const float*)d_in[25];
    const float* wmaster_b=(const float*)d_in[26];
    const float* wm2m_w= (const float*)d_in[27];
    const float* wm2m_b= (const float*)d_in[28];
    const float* wzm1_w= (const float*)d_in[29];
    const float* wzm1_b= (const float*)d_in[30];
    const float* wzm2_w= (const float*)d_in[31];
    const float* wzm2_b= (const float*)d_in[32];
    const float* wzs1_w= (const float*)d_in[33];
    const float* wzs1_b= (const float*)d_in[34];
    const float* wzs2_w= (const float*)d_in[35];
    const float* wzs2_b= (const float*)d_in[36];
    const float* g_wih = (const float*)d_in[37];
    const float* g_whh = (const float*)d_in[38];
    const float* g_bih = (const float*)d_in[39];
    const float* g_bhh = (const float*)d_in[40];
    const float* gm_wih= (const float*)d_in[41];
    const float* gm_whh= (const float*)d_in[42];
    const float* gm_bih= (const float*)d_in[43];
    const float* gm_bhh= (const float*)d_in[44];

    float* ws     = (float*)d_ws;
    float* vf     = ws;
    float* h0     = vf + SLAB;
    float* S      = h0 + SLAB;            // 4 slabs
    float* e_init = S + 4*(size_t)SLAB;
    float* att    = e_init + BB*EE*BF;
    float* kmm    = att + BB*KK*NN;
    float* master = kmm + BB*KK*HH;
    float* m2m    = master + BB*HH;
    float* t2     = m2m + BB*HH;
    float* WTih_s = t2 + BB*HH;
    float* WThh_s = WTih_s + 128*384;
    // bf16 hi/lo weight tables (as short); each table is 2*total shorts
    short* wt_emb   = (short*)(WThh_s + 128*384);
    short* wt_wvm   = wt_emb   + 2*12288;
    short* wt_wmain = wt_wvm   + 2*196608;
    short* wt_u1    = wt_wmain + 2*196608;
    short* wt_u2    = wt_u1    + 2*61440;
    short* wt_fu    = wt_u2    + 2*98304;
    short* wt_wzm1  = wt_fu    + 2*49152;
    short* wt_gih   = wt_wzm1  + 2*49152;
    short* wt_ghh   = wt_gih   + 2*49152;

    const float* NPF = nullptr;
    const int*   NPI = nullptr;
    float*       NPW = nullptr;

    // master-GRU fp32 transposes
    transpose384_kernel<<<192, 256, 0, stream>>>(gm_wih, WTih_s);
    transpose384_kernel<<<192, 256, 0, stream>>>(gm_whh, WThh_s);

    // bf16 hi/lo weight conversions
    wcvt_t<<<(12288+255)/256,     256, 0, stream>>>(emb_w,   wt_emb,   82, 96, 12288);
    wcvt_t<<<(196608+255)/256,    256, 0, stream>>>(wvm_w,   wt_wvm,  128,128, 196608);
    wcvt_t<<<(196608+255)/256,    256, 0, stream>>>(wmain_w, wt_wmain,128,128, 196608);
    wcvt_t<<<(61440+255)/256,     256, 0, stream>>>(u1_w,    wt_u1,   134,160, 61440);
    wcvt_t<<<(98304+255)/256,     256, 0, stream>>>(u2_w,    wt_u2,   256,256, 98304);
    wcvt_t<<<(49152+255)/256,     256, 0, stream>>>(fu_w,    wt_fu,   128,128, 49152);
    wcvt_t<<<(49152+255)/256,     256, 0, stream>>>(wzm1_w,  wt_wzm1, 128,128, 49152);
    wcvt_d<<<(49152+255)/256,     256, 0, stream>>>(g_wih,   wt_gih,  49152);
    wcvt_d<<<(49152+255)/256,     256, 0, stream>>>(g_whh,   wt_ghh,  49152);

    e_gather_kernel<<<(BB*EE*BF + 255)/256, 256, 0, stream>>>(bondf, edge, e_init);

    // embed: vf = gelu((atomf[vertex]*vm) @ emb_w + b), dual store h0
    mgemm<1,1><<<dim3(256,1,1), 256, 0, stream>>>(
        atomf, NPF, wt_emb, emb_b, vf, h0, AF, 96,
        vertex, NPI, vmask, NPF, NPF, NPF, NPF, 0.f, 0.f, 1, 0ULL, 0ULL, 12288ULL);

    master_init_kernel<<<BB, 256, 0, stream>>>(vf, vmask, master);

    for (int i = 0; i < LL; ++i) {
        float theta = logf(0.5f/(float)(i+1) + 1.f);

        // mv = tanh(vf @ wvm[i,k] + b) -> S[k]
        mgemm<0,2><<<dim3(256,1,4), 256, 0, stream>>>(
            vf, NPF, wt_wvm + (size_t)i*4*16384, wvm_b + (size_t)i*4*128, S, NPW, 128, 128,
            NPI, NPI, NPF, NPF, NPF, NPF, NPF, 0.f, 0.f, 1,
            (unsigned long long)SLAB, 16384ULL, 196608ULL);
        score_kernel<<<BB*KK*NN/4, 256, 0, stream>>>(S, master, wbmm_w + i*KK*HH, wbmm_b + i*KK, att);
        softmax_kernel<<<BB*KK, 256, 0, stream>>>(att, vmask);
        // proj = vf @ wmain[i,k] + b -> S[k]
        mgemm<0,0><<<dim3(256,1,4), 256, 0, stream>>>(
            vf, NPF, wt_wmain + (size_t)i*4*16384, wmain_b + (size_t)i*4*128, S, NPW, 128, 128,
            NPI, NPI, NPF, NPF, NPF, NPF, NPF, 0.f, 0.f, 1,
            (unsigned long long)SLAB, 16384ULL, 196608ULL);
        kmm_kernel<<<BB*KK, 128, 0, stream>>>(S, att, kmm);

        // fused master path: mtm, m2m, mself, t2, hidden_super, master GRU
        master_fused<<<BB, 256, 0, stream>>>(
            kmm, master,
            khead_w + (size_t)i*KK*HH*HH, khead_b + i*HH,
            wm2m_w + (size_t)i*HH*HH, wm2m_b + i*HH,
            wmaster_w + (size_t)i*HH*HH, wmaster_b + i*HH,
            wzm2_w + (size_t)i*HH*HH, wzm2_b + i*HH,
            wzs1_w + (size_t)i*HH*HH, wzs1_b + i*HH,
            wzs2_w + (size_t)i*HH*HH, wzs2_b + i*HH,
            WTih_s, WThh_s, gm_bih, gm_bhh,
            m2m, t2);

        // u1 -> nl in S0
        mgemm<3,5><<<dim3(2048,1,1), 256, 0, stream>>>(
            vf, e_init, wt_u1 + (size_t)i*128*160, u1_b + i*HH, S, NPW, 134, 160,
            aadj, badj, NPF, nbm, NPF, NPF, NPF, 0.f, 0.f, 1, 0ULL, 0ULL, 61440ULL);
        // u2: hi = concat(nl, vf) @ u2 + b -> S1
        mgemm<2,0><<<dim3(256,1,1), 256, 0, stream>>>(
            S, vf, wt_u2 + (size_t)i*128*256, u2_b + i*HH, S + SLAB, NPW, 256, 256,
            NPI, NPI, NPF, NPF, NPF, NPF, NPF, 0.f, 0.f, 1, 0ULL, 0ULL, 98304ULL);
        pw_support_kernel<<<4096, 256, 0, stream>>>(S + SLAB, h0);
        // self_vertex -> S2
        mgemm<0,3><<<dim3(256,1,1), 256, 0, stream>>>(
            S + SLAB, NPF, wt_fu + (size_t)i*16384, fu_b + i*HH, S + 2*(size_t)SLAB, NPW, 128, 128,
            NPI, NPI, NPF, NPF, S + SLAB, NPF, NPF, theta, 1.f - theta, 1, 0ULL, 0ULL, 49152ULL);
        // hidden_main -> S3 (z-gate with t2, m2m from master_fused)
        mgemm<0,4><<<dim3(256,1,1), 256, 0, stream>>>(
            S + 2*(size_t)SLAB, NPF, wt_wzm1 + (size_t)i*16384, wzm1_b + i*HH, S + 3*(size_t)SLAB, NPW, 128, 128,
            NPI, NPI, NPF, NPF, S + 2*(size_t)SLAB, t2, m2m, 0.f, 0.f, NN, 0ULL, 0ULL, 49152ULL);
        // gi = hidden_main @ wih^T + bih, 3 gate slabs -> S0..S2
        mgemm<0,0><<<dim3(256,1,3), 256, 0, stream>>>(
            S + 3*(size_t)SLAB, NPF, wt_gih, g_bih, S, NPW, 128, 128,
            NPI, NPI, NPF, NPF, NPF, NPF, NPF, 0.f, 0.f, 1,
            (unsigned long long)SLAB, 16384ULL, 49152ULL);
        // vf = GRU(hidden_main, vf) fused gh-MFMA + combine
        gru_mfma<<<dim3(512,1,1), 256, 0, stream>>>(S, vf, wt_ghh, g_bhh, 49152ULL);
    }

    copy_out_kernel<<<(SLAB + BB*HH)/4/256, 256, 0, stream>>>(vf, master, (float*)d_out);
}

// Round 5
// 1607.097 us; speedup vs baseline: 2.6941x; 1.0131x over previous
//
#include <hip/hip_runtime.h>
#include <hip/hip_bf16.h>
#include <cmath>

// Problem constants
#define BB 64
#define NN 512
#define NBS 8
#define EE 2048
#define HH 128
#define LL 3
#define KK 4
#define AF 82
#define BF 6
#define SLAB 4194304   // B*N*H floats

typedef __attribute__((ext_vector_type(8))) short bf16x8;
typedef __attribute__((ext_vector_type(4))) float f32x4;

__device__ __forceinline__ float gelu1(float x){ return 0.5f*x*(1.f+erff(x*0.7071067811865475f)); }
__device__ __forceinline__ float sig1(float x){ return 1.f/(1.f+expf(-x)); }
__device__ __forceinline__ short f2bs(float x){ __hip_bfloat16 b=__float2bfloat16(x); return *reinterpret_cast<short*>(&b); }
__device__ __forceinline__ float bs2f(short s){ unsigned u = ((unsigned)(unsigned short)s) << 16; union{unsigned u; float f;} c; c.u=u; return c.f; }
__device__ __forceinline__ void split2(float v, short& hi, short& lo){ hi = f2bs(v); lo = f2bs(v - bs2f(hi)); }

// ---------------------------------------------------------------------------
// Split-bf16 (emulated fp32) MFMA GEMM: C[M,128] = epi(A[M,K] @ W[K,128] + b)
// Weight tables: hi at WT[col*KPAD+k], lo at WT[loOff + col*KPAD+k].
// AMODE: 0 contiguous fp32 A (stride K); 1 atom-gather*vmask; 2 concat(A,A2);
//        3 u1 gather; 4 blend 0.9*A+0.1*A2 (stride 128)
// EMODE: 0 bias; 1 gelu(+C2); 4 z-gate; 5 u1 segsum;
//        6 theta-blend vs support: v=p0*(acc+b)+p1*(0.9*extraM+0.1*extraB2)
// ---------------------------------------------------------------------------
template<int AMODE, int EMODE, int KPAD>
__global__ __launch_bounds__(256) void mgemm(
    const float* __restrict__ A, const float* __restrict__ A2,
    const short* __restrict__ WT, const float* __restrict__ bias,
    float* __restrict__ C, float* __restrict__ C2,
    int K,
    const int* __restrict__ g1, const int* __restrict__ g2,
    const float* __restrict__ vmask, const float* __restrict__ nbm,
    const float* __restrict__ extraM, const float* __restrict__ extraB,
    const float* __restrict__ extraB2,
    float p0, float p1, int rowsPerB,
    unsigned long long zCs, unsigned long long zWs, unsigned long long loOff)
{
    const int t = threadIdx.x;
    const int lane = t & 63, wv = t >> 6;
    const int quad = lane >> 4, ml = lane & 15;
    const int z = blockIdx.z;
    const short* WTz = WT + (size_t)z * zWs;
    const float* bz  = bias + (size_t)z * 128;
    float* Cz        = C + (size_t)z * zCs;
    const int m0 = blockIdx.x * 128 + wv * 32;

    const int r0 = m0 + ml, r1 = m0 + 16 + ml;
    int ga0 = 0, ga1 = 0, gb0 = 0, gb1 = 0; float vm0 = 0.f, vm1 = 0.f;
    if (AMODE == 1) { ga0 = g1[r0]; ga1 = g1[r1]; vm0 = vmask[r0]; vm1 = vmask[r1]; }
    if (AMODE == 3) { ga0 = g1[r0]; ga1 = g1[r1]; gb0 = g2[r0]; gb1 = g2[r1]; }

    f32x4 acc[16];
    #pragma unroll
    for (int i = 0; i < 16; ++i) acc[i] = (f32x4){0.f,0.f,0.f,0.f};

    constexpr int nchunk = KPAD >> 5;
    const short* wcol = WTz + (size_t)ml * KPAD;

    #pragma unroll
    for (int kc = 0; kc < nchunk; ++kc) {
        const int kq = kc*32 + quad*8;
        float av0[8], av1[8];
        if (AMODE == 0) {
            const float* p0r = A + (size_t)r0*K + kq;
            const float* p1r = A + (size_t)r1*K + kq;
            float4 a0 = *(const float4*)p0r, a1 = *(const float4*)(p0r+4);
            float4 b0 = *(const float4*)p1r, b1 = *(const float4*)(p1r+4);
            av0[0]=a0.x; av0[1]=a0.y; av0[2]=a0.z; av0[3]=a0.w;
            av0[4]=a1.x; av0[5]=a1.y; av0[6]=a1.z; av0[7]=a1.w;
            av1[0]=b0.x; av1[1]=b0.y; av1[2]=b0.z; av1[3]=b0.w;
            av1[4]=b1.x; av1[5]=b1.y; av1[6]=b1.z; av1[7]=b1.w;
        } else if (AMODE == 1) {
            const float* p0r = A + (size_t)ga0*K + kq;
            const float* p1r = A + (size_t)ga1*K + kq;
            #pragma unroll
            for (int j2 = 0; j2 < 4; ++j2) {
                int k = kq + 2*j2;
                if (k + 2 <= K) {
                    float2 v0 = *(const float2*)(p0r + 2*j2);
                    float2 v1 = *(const float2*)(p1r + 2*j2);
                    av0[2*j2]=v0.x*vm0; av0[2*j2+1]=v0.y*vm0;
                    av1[2*j2]=v1.x*vm1; av1[2*j2+1]=v1.y*vm1;
                } else { av0[2*j2]=0.f; av0[2*j2+1]=0.f; av1[2*j2]=0.f; av1[2*j2+1]=0.f; }
            }
        } else if (AMODE == 2) {
            const float* p0r = (kq < 128) ? A + (size_t)r0*128 + kq : A2 + (size_t)r0*128 + (kq-128);
            const float* p1r = (kq < 128) ? A + (size_t)r1*128 + kq : A2 + (size_t)r1*128 + (kq-128);
            float4 a0 = *(const float4*)p0r, a1 = *(const float4*)(p0r+4);
            float4 b0 = *(const float4*)p1r, b1 = *(const float4*)(p1r+4);
            av0[0]=a0.x; av0[1]=a0.y; av0[2]=a0.z; av0[3]=a0.w;
            av0[4]=a1.x; av0[5]=a1.y; av0[6]=a1.z; av0[7]=a1.w;
            av1[0]=b0.x; av1[1]=b0.y; av1[2]=b0.z; av1[3]=b0.w;
            av1[4]=b1.x; av1[5]=b1.y; av1[6]=b1.z; av1[7]=b1.w;
        } else if (AMODE == 4) {
            const float* p0r = A  + (size_t)r0*128 + kq;
            const float* q0r = A2 + (size_t)r0*128 + kq;
            const float* p1r = A  + (size_t)r1*128 + kq;
            const float* q1r = A2 + (size_t)r1*128 + kq;
            float4 a0 = *(const float4*)p0r, a1 = *(const float4*)(p0r+4);
            float4 c0 = *(const float4*)q0r, c1 = *(const float4*)(q0r+4);
            float4 b0 = *(const float4*)p1r, b1 = *(const float4*)(p1r+4);
            float4 d0 = *(const float4*)q1r, d1 = *(const float4*)(q1r+4);
            av0[0]=0.9f*a0.x+0.1f*c0.x; av0[1]=0.9f*a0.y+0.1f*c0.y;
            av0[2]=0.9f*a0.z+0.1f*c0.z; av0[3]=0.9f*a0.w+0.1f*c0.w;
            av0[4]=0.9f*a1.x+0.1f*c1.x; av0[5]=0.9f*a1.y+0.1f*c1.y;
            av0[6]=0.9f*a1.z+0.1f*c1.z; av0[7]=0.9f*a1.w+0.1f*c1.w;
            av1[0]=0.9f*b0.x+0.1f*d0.x; av1[1]=0.9f*b0.y+0.1f*d0.y;
            av1[2]=0.9f*b0.z+0.1f*d0.z; av1[3]=0.9f*b0.w+0.1f*d0.w;
            av1[4]=0.9f*b1.x+0.1f*d1.x; av1[5]=0.9f*b1.y+0.1f*d1.y;
            av1[6]=0.9f*b1.z+0.1f*d1.z; av1[7]=0.9f*b1.w+0.1f*d1.w;
        } else { // AMODE 3
            if (kq < 128) {
                const float* p0r = A + (size_t)ga0*128 + kq;
                const float* p1r = A + (size_t)ga1*128 + kq;
                float4 a0 = *(const float4*)p0r, a1 = *(const float4*)(p0r+4);
                float4 b0 = *(const float4*)p1r, b1 = *(const float4*)(p1r+4);
                av0[0]=a0.x; av0[1]=a0.y; av0[2]=a0.z; av0[3]=a0.w;
                av0[4]=a1.x; av0[5]=a1.y; av0[6]=a1.z; av0[7]=a1.w;
                av1[0]=b0.x; av1[1]=b0.y; av1[2]=b0.z; av1[3]=b0.w;
                av1[4]=b1.x; av1[5]=b1.y; av1[6]=b1.z; av1[7]=b1.w;
            } else if (kq == 128) {
                const float* p0r = A2 + (size_t)gb0*6;
                const float* p1r = A2 + (size_t)gb1*6;
                float2 x0=*(const float2*)p0r, x1=*(const float2*)(p0r+2), x2=*(const float2*)(p0r+4);
                float2 y0=*(const float2*)p1r, y1=*(const float2*)(p1r+2), y2=*(const float2*)(p1r+4);
                av0[0]=x0.x; av0[1]=x0.y; av0[2]=x1.x; av0[3]=x1.y; av0[4]=x2.x; av0[5]=x2.y; av0[6]=0.f; av0[7]=0.f;
                av1[0]=y0.x; av1[1]=y0.y; av1[2]=y1.x; av1[3]=y1.y; av1[4]=y2.x; av1[5]=y2.y; av1[6]=0.f; av1[7]=0.f;
            } else {
                #pragma unroll
                for (int j = 0; j < 8; ++j) { av0[j]=0.f; av1[j]=0.f; }
            }
        }
        bf16x8 a0h, a0l, a1h, a1l;
        #pragma unroll
        for (int j = 0; j < 8; ++j) {
            short h, l;
            split2(av0[j], h, l); a0h[j]=h; a0l[j]=l;
            split2(av1[j], h, l); a1h[j]=h; a1l[j]=l;
        }

        #pragma unroll
        for (int nt = 0; nt < 8; ++nt) {
            const short* bp = wcol + (size_t)nt*16*KPAD + kq;
            bf16x8 bh = *(const bf16x8*)bp;
            bf16x8 bl = *(const bf16x8*)(bp + loOff);
            acc[nt] = __builtin_amdgcn_mfma_f32_16x16x32_bf16(a0h, bh, acc[nt], 0,0,0);
            acc[nt] = __builtin_amdgcn_mfma_f32_16x16x32_bf16(a0l, bh, acc[nt], 0,0,0);
            acc[nt] = __builtin_amdgcn_mfma_f32_16x16x32_bf16(a0h, bl, acc[nt], 0,0,0);
            acc[8+nt] = __builtin_amdgcn_mfma_f32_16x16x32_bf16(a1h, bh, acc[8+nt], 0,0,0);
            acc[8+nt] = __builtin_amdgcn_mfma_f32_16x16x32_bf16(a1l, bh, acc[8+nt], 0,0,0);
            acc[8+nt] = __builtin_amdgcn_mfma_f32_16x16x32_bf16(a1h, bl, acc[8+nt], 0,0,0);
        }
    }

    // --- epilogue ---
    if constexpr (EMODE == 5) {
        __shared__ float red[4][16][132];
        #pragma unroll
        for (int mt = 0; mt < 2; ++mt) {
            __syncthreads();
            #pragma unroll
            for (int nt = 0; nt < 8; ++nt) {
                int col = nt*16 + ml;
                float bj = bz[col];
                #pragma unroll
                for (int r = 0; r < 4; ++r) {
                    int gm = m0 + mt*16 + quad*4 + r;
                    red[wv][quad*4+r][col] = gelu1(acc[mt*8+nt][r] + bj) * nbm[gm];
                }
            }
            __syncthreads();
            #pragma unroll
            for (int q = 0; q < 4; ++q) {
                int idx = lane*4 + q;
                int seg = idx >> 7, col = idx & 127;
                float s = 0.f;
                #pragma unroll
                for (int ss = 0; ss < 8; ++ss) s += red[wv][seg*8+ss][col];
                Cz[(size_t)(m0/8 + mt*2 + seg)*128 + col] = s;
            }
        }
        return;
    }

    #pragma unroll
    for (int mt = 0; mt < 2; ++mt) {
        #pragma unroll
        for (int nt = 0; nt < 8; ++nt) {
            int col = nt*16 + ml;
            float bj = bz[col];
            #pragma unroll
            for (int r = 0; r < 4; ++r) {
                int gm = m0 + mt*16 + quad*4 + r;
                float v = acc[mt*8+nt][r] + bj;
                if (EMODE == 1) v = gelu1(v);
                else if (EMODE == 4) {
                    int bi = gm / rowsPerB;
                    float zg = sig1(v + extraB[(size_t)bi*128 + col]);
                    v = (1.f-zg)*extraM[(size_t)gm*128 + col] + zg*extraB2[(size_t)bi*128 + col];
                }
                else if (EMODE == 6) {
                    float sup = 0.9f*extraM[(size_t)gm*128 + col] + 0.1f*extraB2[(size_t)gm*128 + col];
                    v = p0*v + p1*sup;
                }
                Cz[(size_t)gm*128 + col] = v;
                if (EMODE == 1 && C2 != nullptr) C2[(size_t)gm*128 + col] = v;
            }
        }
    }
}

// ---------------------------------------------------------------------------
// Fused mv+score: score[b,k,n] = sum_d tanh(vf[b,n]@wvm[k] + b)[d]*master[b,d]*wbmm[k,d] + wbb[k]
// grid.x = B*4 (b, n-tile of 128), grid.z = K. No mv materialization.
// ---------------------------------------------------------------------------
__global__ __launch_bounds__(256) void mvscore_kernel(
    const float* __restrict__ vf,
    const short* __restrict__ WT, const float* __restrict__ bias,  // layer slices
    const float* __restrict__ master,
    const float* __restrict__ wbw, const float* __restrict__ wbb,
    float* __restrict__ score, unsigned long long loOff)
{
    const int t = threadIdx.x;
    const int lane = t & 63, wv = t >> 6;
    const int quad = lane >> 4, ml = lane & 15;
    const int k = blockIdx.z;
    const int b = blockIdx.x >> 2, ntile = blockIdx.x & 3;
    const short* WTz = WT + (size_t)k * 16384;
    const float* bz  = bias + (size_t)k * 128;
    const int nloc0 = ntile*128 + wv*32;
    const int base = b*512 + nloc0;
    const int r0 = base + ml, r1 = base + 16 + ml;

    f32x4 acc[16];
    #pragma unroll
    for (int i = 0; i < 16; ++i) acc[i] = (f32x4){0.f,0.f,0.f,0.f};
    const short* wcol = WTz + (size_t)ml * 128;

    #pragma unroll
    for (int kc = 0; kc < 4; ++kc) {
        const int kq = kc*32 + quad*8;
        const float* p0r = vf + (size_t)r0*128 + kq;
        const float* p1r = vf + (size_t)r1*128 + kq;
        float4 a0 = *(const float4*)p0r, a1 = *(const float4*)(p0r+4);
        float4 b0 = *(const float4*)p1r, b1 = *(const float4*)(p1r+4);
        float av0[8] = {a0.x,a0.y,a0.z,a0.w,a1.x,a1.y,a1.z,a1.w};
        float av1[8] = {b0.x,b0.y,b0.z,b0.w,b1.x,b1.y,b1.z,b1.w};
        bf16x8 a0h, a0l, a1h, a1l;
        #pragma unroll
        for (int j = 0; j < 8; ++j) {
            short h, l;
            split2(av0[j], h, l); a0h[j]=h; a0l[j]=l;
            split2(av1[j], h, l); a1h[j]=h; a1l[j]=l;
        }
        #pragma unroll
        for (int nt = 0; nt < 8; ++nt) {
            const short* bp = wcol + (size_t)nt*16*128 + kq;
            bf16x8 bh = *(const bf16x8*)bp;
            bf16x8 bl = *(const bf16x8*)(bp + loOff);
            acc[nt] = __builtin_amdgcn_mfma_f32_16x16x32_bf16(a0h, bh, acc[nt], 0,0,0);
            acc[nt] = __builtin_amdgcn_mfma_f32_16x16x32_bf16(a0l, bh, acc[nt], 0,0,0);
            acc[nt] = __builtin_amdgcn_mfma_f32_16x16x32_bf16(a0h, bl, acc[nt], 0,0,0);
            acc[8+nt] = __builtin_amdgcn_mfma_f32_16x16x32_bf16(a1h, bh, acc[8+nt], 0,0,0);
            acc[8+nt] = __builtin_amdgcn_mfma_f32_16x16x32_bf16(a1l, bh, acc[8+nt], 0,0,0);
            acc[8+nt] = __builtin_amdgcn_mfma_f32_16x16x32_bf16(a1h, bl, acc[8+nt], 0,0,0);
        }
    }

    // epilogue: tanh, weight by master*wbmm, row-reduce over cols
    float wv8[8];
    float bj8[8];
    #pragma unroll
    for (int nt = 0; nt < 8; ++nt) {
        int col = nt*16 + ml;
        wv8[nt] = master[(size_t)b*128 + col] * wbw[(size_t)k*128 + col];
        bj8[nt] = bz[col];
    }
    float kb = wbb[k];
    #pragma unroll
    for (int mt = 0; mt < 2; ++mt) {
        #pragma unroll
        for (int r = 0; r < 4; ++r) {
            float s = 0.f;
            #pragma unroll
            for (int nt = 0; nt < 8; ++nt)
                s += tanhf(acc[mt*8+nt][r] + bj8[nt]) * wv8[nt];
            s += __shfl_xor(s, 1); s += __shfl_xor(s, 2);
            s += __shfl_xor(s, 4); s += __shfl_xor(s, 8);
            if (ml == 0) {
                int nloc = nloc0 + mt*16 + quad*4 + r;
                score[((size_t)(b*KK + k))*NN + nloc] = s + kb;
            }
        }
    }
}

// ---------------------------------------------------------------------------
// ctx[b,k,d] = sum_n att[b,k,n] * vf[b,n,d]
// ---------------------------------------------------------------------------
__global__ __launch_bounds__(128) void ctx_kernel(const float* __restrict__ vf,
                                                  const float* __restrict__ att,
                                                  float* __restrict__ ctx)
{
    int bk = blockIdx.x; int b = bk >> 2;
    int d = threadIdx.x;
    const float* at = att + (size_t)bk*NN;
    const float* V = vf + (size_t)b*NN*HH;
    float acc = 0.f;
    #pragma unroll 4
    for (int n = 0; n < NN; ++n) acc += at[n]*V[(size_t)n*HH + d];
    ctx[(size_t)bk*HH + d] = acc;
}

// ---------------------------------------------------------------------------
// Fused GRU: gi = x@wih^T, gh = h@whh^T via split-bf16 MFMA, gate math, vf inplace.
// Wave: 16 rows x half of the 3x128 gate cols. Block 256 = 32 rows. grid = B*N/32.
// ---------------------------------------------------------------------------
__global__ __launch_bounds__(256) void gru_fused(
    const float* __restrict__ x,     // hidden_main
    float* __restrict__ vf,
    const short* __restrict__ wih,   // [384][128] bf16 direct, lo at +loOff
    const short* __restrict__ whh,
    const float* __restrict__ bih, const float* __restrict__ bhh,
    unsigned long long loOff)
{
    const int t = threadIdx.x;
    const int lane = t & 63, wv = t >> 6;
    const int quad = lane >> 4, ml = lane & 15;
    const int rg = wv >> 1, ch = wv & 1;
    const int base = blockIdx.x * 32 + rg * 16;
    const int arow = base + ml;

    f32x4 ai[12], ah2[12];
    #pragma unroll
    for (int i = 0; i < 12; ++i) { ai[i] = (f32x4){0.f,0.f,0.f,0.f}; ah2[i] = (f32x4){0.f,0.f,0.f,0.f}; }

    #pragma unroll
    for (int kc = 0; kc < 4; ++kc) {
        const int kq = kc*32 + quad*8;
        const float* px = x  + (size_t)arow*128 + kq;
        const float* ph = vf + (size_t)arow*128 + kq;
        float4 x0 = *(const float4*)px, x1 = *(const float4*)(px+4);
        float4 h0v = *(const float4*)ph, h1v = *(const float4*)(ph+4);
        float xa[8] = {x0.x,x0.y,x0.z,x0.w,x1.x,x1.y,x1.z,x1.w};
        float ha[8] = {h0v.x,h0v.y,h0v.z,h0v.w,h1v.x,h1v.y,h1v.z,h1v.w};
        bf16x8 xh, xl, hh, hl;
        #pragma unroll
        for (int j = 0; j < 8; ++j) {
            short h_, l_;
            split2(xa[j], h_, l_); xh[j]=h_; xl[j]=l_;
            split2(ha[j], h_, l_); hh[j]=h_; hl[j]=l_;
        }
        #pragma unroll
        for (int g = 0; g < 3; ++g) {
            #pragma unroll
            for (int nt = 0; nt < 4; ++nt) {
                int idx = g*4 + nt;
                int colrow = g*128 + ch*64 + nt*16 + ml;
                const short* bpi = wih + (size_t)colrow*128 + kq;
                const short* bph = whh + (size_t)colrow*128 + kq;
                bf16x8 bhI = *(const bf16x8*)bpi;
                bf16x8 blI = *(const bf16x8*)(bpi + loOff);
                bf16x8 bhH = *(const bf16x8*)bph;
                bf16x8 blH = *(const bf16x8*)(bph + loOff);
                ai[idx] = __builtin_amdgcn_mfma_f32_16x16x32_bf16(xh, bhI, ai[idx], 0,0,0);
                ai[idx] = __builtin_amdgcn_mfma_f32_16x16x32_bf16(xl, bhI, ai[idx], 0,0,0);
                ai[idx] = __builtin_amdgcn_mfma_f32_16x16x32_bf16(xh, blI, ai[idx], 0,0,0);
                ah2[idx] = __builtin_amdgcn_mfma_f32_16x16x32_bf16(hh, bhH, ah2[idx], 0,0,0);
                ah2[idx] = __builtin_amdgcn_mfma_f32_16x16x32_bf16(hl, bhH, ah2[idx], 0,0,0);
                ah2[idx] = __builtin_amdgcn_mfma_f32_16x16x32_bf16(hh, blH, ah2[idx], 0,0,0);
            }
        }
    }

    #pragma unroll
    for (int nt = 0; nt < 4; ++nt) {
        int col = ch*64 + nt*16 + ml;
        float bir = bih[col],     bhr = bhh[col];
        float biz = bih[128+col], bhz = bhh[128+col];
        float bin = bih[256+col], bhn = bhh[256+col];
        #pragma unroll
        for (int r = 0; r < 4; ++r) {
            int row = base + quad*4 + r;
            size_t off = (size_t)row*128 + col;
            float gr = sig1(ai[nt][r] + bir + ah2[nt][r] + bhr);
            float gz = sig1(ai[4+nt][r] + biz + ah2[4+nt][r] + bhz);
            float gn = tanhf(ai[8+nt][r] + bin + gr*(ah2[8+nt][r] + bhn));
            float hv = vf[off];
            vf[off] = (1.f-gz)*gn + gz*hv;
        }
    }
}

// ---------------------------------------------------------------------------
// Fused master path (per layer): kmm from ctx, mtm, m2m, mself, t2, hidden_super,
// master GRU. grid=64 blocks (one per batch row).
// ---------------------------------------------------------------------------
__global__ __launch_bounds__(256) void master_fused(
    const float* __restrict__ ctx,        // [B][K][128]
    const float* __restrict__ satt,       // [B][K]
    float* __restrict__ master,           // [B][128] in/out
    const float* __restrict__ wmain_w, const float* __restrict__ wmain_b,  // [K][128][128],[K][128]
    const float* __restrict__ khead_w, const float* __restrict__ khead_b,
    const float* __restrict__ wm2m_w,  const float* __restrict__ wm2m_b,
    const float* __restrict__ wmaster_w, const float* __restrict__ wmaster_b,
    const float* __restrict__ wzm2_w,  const float* __restrict__ wzm2_b,
    const float* __restrict__ wzs1_w,  const float* __restrict__ wzs1_b,
    const float* __restrict__ wzs2_w,  const float* __restrict__ wzs2_b,
    const float* __restrict__ WTih, const float* __restrict__ WThh,  // [128][384]
    const float* __restrict__ bih, const float* __restrict__ bhh,
    float* __restrict__ m2m_out, float* __restrict__ t2_out)
{
    __shared__ float xs[512], ms[128];
    __shared__ float v_mtm[128], v_m2m[128], v_mself[128], v_t2[128];
    __shared__ float v_ts1[128], v_ts2[128], v_hsup[128];
    __shared__ float gi[384], gh[384];
    __shared__ float red[256];
    const int t = threadIdx.x;
    const int b = blockIdx.x;

    if (t < 128) ms[t] = master[(size_t)b*128 + t];
    __syncthreads();

    const int c = t & 127, p = t >> 7;

    // kmm[k] = ctx[k] @ wmain[k] + satt[k]*wmain_b[k]
    #pragma unroll
    for (int k = 0; k < 4; ++k) {
        const float* cx = ctx + ((size_t)b*KK + k)*128;
        const float* Wk = wmain_w + (size_t)k*16384;
        float s = 0.f;
        for (int d = p*64; d < p*64+64; ++d) s += cx[d]*Wk[(size_t)d*128 + c];
        red[t] = s; __syncthreads();
        if (t < 128) xs[k*128 + c] = red[c] + red[c+128] + satt[(size_t)b*KK + k]*wmain_b[k*128 + c];
        __syncthreads();
    }

    auto matvec = [&](const float* src, const float* __restrict__ W,
                      const float* __restrict__ bias, int K, float* out, int act) {
        int half = K >> 1;
        int k0 = p*half, k1 = k0 + half;
        float s = 0.f;
        for (int k = k0; k < k1; ++k) s += src[k]*W[(size_t)k*128 + c];
        red[t] = s; __syncthreads();
        if (t < 128) {
            float v = red[c] + red[c+128] + bias[c];
            if (act == 1) v = gelu1(v); else if (act == 2) v = tanhf(v);
            out[c] = v;
        }
        __syncthreads();
    };

    matvec(xs, khead_w, khead_b, 512, v_mtm, 2);
    matvec(ms, wm2m_w, wm2m_b, 128, v_m2m, 1);
    matvec(ms, wmaster_w, wmaster_b, 128, v_mself, 1);
    matvec(v_m2m, wzm2_w, wzm2_b, 128, v_t2, 0);
    matvec(v_mself, wzs1_w, wzs1_b, 128, v_ts1, 0);
    matvec(v_mtm, wzs2_w, wzs2_b, 128, v_ts2, 0);

    if (t < 128) {
        float z = sig1(v_ts1[t] + v_ts2[t]);
        v_hsup[t] = (1.f-z)*v_mself[t] + z*v_mtm[t];
        m2m_out[(size_t)b*128 + t] = v_m2m[t];
        t2_out[(size_t)b*128 + t]  = v_t2[t];
    }
    __syncthreads();

    for (int j = t; j < 384; j += 256) {
        float a = 0.f, h2 = 0.f;
        for (int k = 0; k < 128; ++k) {
            a  += v_hsup[k]*WTih[(size_t)k*384 + j];
            h2 += ms[k]*WThh[(size_t)k*384 + j];
        }
        gi[j] = a + bih[j];
        gh[j] = h2 + bhh[j];
    }
    __syncthreads();
    if (t < 128) {
        float r = sig1(gi[t] + gh[t]);
        float z = sig1(gi[128+t] + gh[128+t]);
        float n = tanhf(gi[256+t] + r*gh[256+t]);
        master[(size_t)b*128 + t] = (1.f-z)*n + z*ms[t];
    }
}

// ---------------------------------------------------------------------------
// Weight conversion: dst[i]=hi, dst[total+i]=lo
__global__ void wcvt_t(const float* __restrict__ src, short* __restrict__ dst,
                       int K, int Kpad, int total)
{
    int i = blockIdx.x*256 + threadIdx.x;
    if (i >= total) return;
    int z = i / (128*Kpad); int rem = i - z*128*Kpad;
    int col = rem / Kpad; int k = rem - col*Kpad;
    float v = (k < K) ? src[(size_t)z*K*128 + (size_t)k*128 + col] : 0.f;
    short h, l; split2(v, h, l);
    dst[i] = h; dst[total + i] = l;
}

__global__ void wcvt_d(const float* __restrict__ src, short* __restrict__ dst, int n)
{
    int i = blockIdx.x*256 + threadIdx.x;
    if (i < n) { short h,l; split2(src[i], h, l); dst[i]=h; dst[n+i]=l; }
}

// ---------------------------------------------------------------------------
// small helper kernels
// ---------------------------------------------------------------------------
__global__ void transpose384_kernel(const float* __restrict__ src, float* __restrict__ dst)
{
    int o = blockIdx.x*256 + threadIdx.x;
    if (o >= 49152) return;
    int k = o / 384, j = o - k*384;
    dst[o] = src[j*128 + k];
}

__global__ void e_gather_kernel(const float* __restrict__ bondf, const int* __restrict__ edge,
                                float* __restrict__ e_init)
{
    int idx = blockIdx.x*256 + threadIdx.x;
    if (idx >= BB*EE*BF) return;
    int m = idx / BF, j = idx - m*BF;
    e_init[idx] = bondf[edge[m]*BF + j];
}

__global__ __launch_bounds__(256) void master_init_kernel(const float* __restrict__ vf,
                                                          const float* __restrict__ vm,
                                                          float* __restrict__ master)
{
    __shared__ float red[256];
    int b = blockIdx.x; int t = threadIdx.x; int hcol = t & 127; int half = t >> 7;
    float s = 0.f;
    for (int n = half; n < NN; n += 2)
        s += vf[((size_t)b*NN + n)*HH + hcol] * vm[b*NN + n];
    red[t] = s; __syncthreads();
    if (half == 0) master[b*HH + hcol] = red[hcol] + red[hcol + 128];
}

__global__ __launch_bounds__(256) void softmax_kernel(float* __restrict__ att,
                                                      const float* __restrict__ vm,
                                                      float* __restrict__ satt)
{
    __shared__ float red[256];
    int t = threadIdx.x;
    int bk = blockIdx.x; int b = bk >> 2;
    float* a = att + (size_t)bk*NN;
    float v0 = a[t], v1 = a[t+256];
    red[t] = fmaxf(v0, v1); __syncthreads();
    for (int s = 128; s; s >>= 1) { if (t < s) red[t] = fmaxf(red[t], red[t+s]); __syncthreads(); }
    float mx = red[0]; __syncthreads();
    float e0 = expf(v0 - mx) * vm[b*NN + t];
    float e1 = expf(v1 - mx) * vm[b*NN + t + 256];
    red[t] = e0 + e1; __syncthreads();
    for (int s = 128; s; s >>= 1) { if (t < s) red[t] += red[t+s]; __syncthreads(); }
    float sum = red[0];
    float inv = 1.f / (sum + 1e-6f);
    a[t] = e0*inv; a[t+256] = e1*inv;
    if (t == 0) satt[bk] = sum*inv;
}

__global__ void copy_out_kernel(const float* __restrict__ vf, const float* __restrict__ master,
                                float* __restrict__ out)
{
    int i = blockIdx.x*256 + threadIdx.x;
    const int nvf4 = SLAB/4;
    if (i < nvf4) ((float4*)out)[i] = ((const float4*)vf)[i];
    else ((float4*)out)[i] = ((const float4*)master)[i - nvf4];
}

// ---------------------------------------------------------------------------
extern "C" void kernel_launch(void* const* d_in, const int* in_sizes, int n_in,
                              void* d_out, int out_size, void* d_ws, size_t ws_size,
                              hipStream_t stream)
{
    (void)in_sizes; (void)n_in; (void)out_size; (void)ws_size;
    const float* vmask = (const float*)d_in[1];
    const int*   vertex= (const int*)d_in[2];
    const int*   edge  = (const int*)d_in[3];
    const int*   aadj  = (const int*)d_in[4];
    const int*   badj  = (const int*)d_in[5];
    const float* nbm   = (const float*)d_in[6];
    const float* atomf = (const float*)d_in[7];
    const float* bondf = (const float*)d_in[8];
    const float* emb_w = (const float*)d_in[9];
    const float* emb_b = (const float*)d_in[10];
    const float* u1_w  = (const float*)d_in[11];
    const float* u1_b  = (const float*)d_in[12];
    const float* u2_w  = (const float*)d_in[13];
    const float* u2_b  = (const float*)d_in[14];
    const float* fu_w  = (const float*)d_in[15];
    const float* fu_b  = (const float*)d_in[16];
    const float* wvm_w = (const float*)d_in[17];
    const float* wvm_b = (const float*)d_in[18];
    const float* wmain_w=(const float*)d_in[19];
    const float* wmain_b=(const float*)d_in[20];
    const float* wbmm_w= (const float*)d_in[21];
    const float* wbmm_b= (const float*)d_in[22];
    const float* khead_w=(const float*)d_in[23];
    const float* khead_b=(const float*)d_in[24];
    const float* wmaster_w=(const float*)d_in[25];
    const float* wmaster_b=(const float*)d_in[26];
    const float* wm2m_w= (const float*)d_in[27];
    const float* wm2m_b= (const float*)d_in[28];
    const float* wzm1_w= (const float*)d_in[29];
    const float* wzm1_b= (const float*)d_in[30];
    const float* wzm2_w= (const float*)d_in[31];
    const float* wzm2_b= (const float*)d_in[32];
    const float* wzs1_w= (const float*)d_in[33];
    const float* wzs1_b= (const float*)d_in[34];
    const float* wzs2_w= (const float*)d_in[35];
    const float* wzs2_b= (const float*)d_in[36];
    const float* g_wih = (const float*)d_in[37];
    const float* g_whh = (const float*)d_in[38];
    const float* g_bih = (const float*)d_in[39];
    const float* g_bhh = (const float*)d_in[40];
    const float* gm_wih= (const float*)d_in[41];
    const float* gm_whh= (const float*)d_in[42];
    const float* gm_bih= (const float*)d_in[43];
    const float* gm_bhh= (const float*)d_in[44];

    float* ws     = (float*)d_ws;
    float* vf     = ws;
    float* h0     = vf + SLAB;
    float* S      = h0 + SLAB;            // 4 slabs: S0=nl, S1=hi, S2=sv, S3=hidden
    float* e_init = S + 4*(size_t)SLAB;
    float* att    = e_init + BB*EE*BF;
    float* ctx    = att + BB*KK*NN;
    float* satt   = ctx + BB*KK*HH;
    float* master = satt + BB*KK;
    float* m2m    = master + BB*HH;
    float* t2     = m2m + BB*HH;
    float* WTih_s = t2 + BB*HH;
    float* WThh_s = WTih_s + 128*384;
    // bf16 hi/lo weight tables (shorts); each table 2*total
    short* wt_emb   = (short*)(WThh_s + 128*384);
    short* wt_wvm   = wt_emb   + 2*12288;
    short* wt_u1    = wt_wvm   + 2*196608;
    short* wt_u2    = wt_u1    + 2*61440;
    short* wt_fu    = wt_u2    + 2*98304;
    short* wt_wzm1  = wt_fu    + 2*49152;
    short* wt_gih   = wt_wzm1  + 2*49152;
    short* wt_ghh   = wt_gih   + 2*49152;

    const float* NPF = nullptr;
    const int*   NPI = nullptr;
    float*       NPW = nullptr;

    transpose384_kernel<<<192, 256, 0, stream>>>(gm_wih, WTih_s);
    transpose384_kernel<<<192, 256, 0, stream>>>(gm_whh, WThh_s);

    wcvt_t<<<(12288+255)/256,     256, 0, stream>>>(emb_w,   wt_emb,   82, 96, 12288);
    wcvt_t<<<(196608+255)/256,    256, 0, stream>>>(wvm_w,   wt_wvm,  128,128, 196608);
    wcvt_t<<<(61440+255)/256,     256, 0, stream>>>(u1_w,    wt_u1,   134,160, 61440);
    wcvt_t<<<(98304+255)/256,     256, 0, stream>>>(u2_w,    wt_u2,   256,256, 98304);
    wcvt_t<<<(49152+255)/256,     256, 0, stream>>>(fu_w,    wt_fu,   128,128, 49152);
    wcvt_t<<<(49152+255)/256,     256, 0, stream>>>(wzm1_w,  wt_wzm1, 128,128, 49152);
    wcvt_d<<<(49152+255)/256,     256, 0, stream>>>(g_wih,   wt_gih,  49152);
    wcvt_d<<<(49152+255)/256,     256, 0, stream>>>(g_whh,   wt_ghh,  49152);

    e_gather_kernel<<<(BB*EE*BF + 255)/256, 256, 0, stream>>>(bondf, edge, e_init);

    // embed: vf = gelu((atomf[vertex]*vm) @ emb_w + b), dual store h0
    mgemm<1,1,96><<<dim3(256,1,1), 256, 0, stream>>>(
        atomf, NPF, wt_emb, emb_b, vf, h0, AF,
        vertex, NPI, vmask, NPF, NPF, NPF, NPF, 0.f, 0.f, 1, 0ULL, 0ULL, 12288ULL);

    master_init_kernel<<<BB, 256, 0, stream>>>(vf, vmask, master);

    for (int i = 0; i < LL; ++i) {
        float theta = logf(0.5f/(float)(i+1) + 1.f);

        // fused mv+score (uses start-of-layer master)
        mvscore_kernel<<<dim3(256,1,4), 256, 0, stream>>>(
            vf, wt_wvm + (size_t)i*4*16384, wvm_b + (size_t)i*4*128,
            master, wbmm_w + (size_t)i*KK*HH, wbmm_b + (size_t)i*KK,
            att, 196608ULL);
        softmax_kernel<<<BB*KK, 256, 0, stream>>>(att, vmask, satt);
        ctx_kernel<<<BB*KK, 128, 0, stream>>>(vf, att, ctx);

        // fused master path: kmm, mtm, m2m, mself, t2, hidden_super, master GRU
        master_fused<<<BB, 256, 0, stream>>>(
            ctx, satt, master,
            wmain_w + (size_t)i*KK*HH*HH, wmain_b + (size_t)i*KK*HH,
            khead_w + (size_t)i*KK*HH*HH, khead_b + i*HH,
            wm2m_w + (size_t)i*HH*HH, wm2m_b + i*HH,
            wmaster_w + (size_t)i*HH*HH, wmaster_b + i*HH,
            wzm2_w + (size_t)i*HH*HH, wzm2_b + i*HH,
            wzs1_w + (size_t)i*HH*HH, wzs1_b + i*HH,
            wzs2_w + (size_t)i*HH*HH, wzs2_b + i*HH,
            WTih_s, WThh_s, gm_bih, gm_bhh,
            m2m, t2);

        // u1 -> nl in S0
        mgemm<3,5,160><<<dim3(2048,1,1), 256, 0, stream>>>(
            vf, e_init, wt_u1 + (size_t)i*128*160, u1_b + i*HH, S, NPW, 134,
            aadj, badj, NPF, nbm, NPF, NPF, NPF, 0.f, 0.f, 1, 0ULL, 0ULL, 61440ULL);
        // u2: hi = concat(nl, vf) @ u2 + b -> S1
        mgemm<2,0,256><<<dim3(256,1,1), 256, 0, stream>>>(
            S, vf, wt_u2 + (size_t)i*128*256, u2_b + i*HH, S + SLAB, NPW, 256,
            NPI, NPI, NPF, NPF, NPF, NPF, NPF, 0.f, 0.f, 1, 0ULL, 0ULL, 98304ULL);
        // self_vertex: A = 0.9*hi+0.1*h0 (blend load), epi blends support again -> S2
        mgemm<4,6,128><<<dim3(256,1,1), 256, 0, stream>>>(
            S + SLAB, h0, wt_fu + (size_t)i*16384, fu_b + i*HH, S + 2*(size_t)SLAB, NPW, 128,
            NPI, NPI, NPF, NPF, S + SLAB, NPF, h0, theta, 1.f - theta, 1, 0ULL, 0ULL, 49152ULL);
        // hidden_main -> S3 (z-gate with t2, m2m)
        mgemm<0,4,128><<<dim3(256,1,1), 256, 0, stream>>>(
            S + 2*(size_t)SLAB, NPF, wt_wzm1 + (size_t)i*16384, wzm1_b + i*HH, S + 3*(size_t)SLAB, NPW, 128,
            NPI, NPI, NPF, NPF, S + 2*(size_t)SLAB, t2, m2m, 0.f, 0.f, NN, 0ULL, 0ULL, 49152ULL);
        // vf = GRU(hidden_main, vf), fully fused gi+gh
        gru_fused<<<dim3(BB*NN/32,1,1), 256, 0, stream>>>(
            S + 3*(size_t)SLAB, vf, wt_gih, wt_ghh, g_bih, g_bhh, 49152ULL);
    }

    copy_out_kernel<<<(SLAB + BB*HH)/4/256, 256, 0, stream>>>(vf, master, (float*)d_out);
}